// Round 1
// baseline (51820.178 us; speedup 1.0000x reference)
//
#include <hip/hip_runtime.h>

#define DD 512
#define MM 4
#define BB 4
#define SS 128
#define KK 32
#define NSTEPS 16
#define EPSF 1e-6f
#define SCALEF 0.04419417382415922f  // 512^-0.5

#define GT 64
#define GK 16

// ---------------- init ----------------
__global__ void k_init(const float* __restrict__ xr, const float* __restrict__ xi,
                       float* __restrict__ sr, float* __restrict__ si,
                       float* __restrict__ acc, float* __restrict__ memv,
                       float* __restrict__ ptrv, float* __restrict__ rem) {
  int idx = blockIdx.x * 256 + threadIdx.x;
  if (idx < BB * SS * 2 * DD) acc[idx] = 0.f;
  if (idx < BB * SS * DD) { sr[idx] = xr[idx]; si[idx] = xi[idx]; }
  if (idx < BB * KK * 2 * DD) memv[idx] = 0.f;
  if (idx < BB * KK) ptrv[idx] = ((idx & (KK - 1)) == 0) ? 1.f : 0.f;
  if (idx < BB) rem[idx] = 1.f;
}

// ---------------- cr/ci = 0.5x + 0.5s ----------------
__global__ void k_prep(const float* __restrict__ xr, const float* __restrict__ xi,
                       const float* __restrict__ sr, const float* __restrict__ si,
                       float* __restrict__ cr, float* __restrict__ ci) {
  int idx = blockIdx.x * 256 + threadIdx.x;
  cr[idx] = 0.5f * xr[idx] + 0.5f * sr[idx];
  ci[idx] = 0.5f * xi[idx] + 0.5f * si[idx];
}

// ---------------- flat_in (mean over S) + control softmax ----------------
__global__ void k_flatctrl(const float* __restrict__ sr, const float* __restrict__ si,
                           const float* __restrict__ ctrl_w, const float* __restrict__ ctrl_b,
                           float* __restrict__ flat_in, float* __restrict__ control) {
  int b = blockIdx.x;
  int tid = threadIdx.x;  // 256
  __shared__ float red[3 * 256];
  float d0 = 0.f, d1 = 0.f, d2 = 0.f;
  for (int i = 0; i < 4; i++) {
    int e = tid + i * 256;  // 0..1023
    const float* basep = (e < DD) ? sr : si;
    int d = (e < DD) ? e : (e - DD);
    float sum = 0.f;
    int base = b * SS * DD + d;
    for (int s = 0; s < SS; s++) sum += basep[base + s * DD];
    float fv = sum * (1.0f / SS);
    flat_in[b * 2 * DD + e] = fv;
    d0 += fv * ctrl_w[e * 3 + 0];
    d1 += fv * ctrl_w[e * 3 + 1];
    d2 += fv * ctrl_w[e * 3 + 2];
  }
  red[tid] = d0; red[256 + tid] = d1; red[512 + tid] = d2;
  __syncthreads();
  for (int off = 128; off > 0; off >>= 1) {
    if (tid < off) {
      red[tid] += red[tid + off];
      red[256 + tid] += red[256 + tid + off];
      red[512 + tid] += red[512 + tid + off];
    }
    __syncthreads();
  }
  if (tid == 0) {
    float l0 = red[0] + ctrl_b[0], l1 = red[256] + ctrl_b[1], l2 = red[512] + ctrl_b[2];
    float mx = fmaxf(l0, fmaxf(l1, l2));
    float e0 = expf(l0 - mx), e1 = expf(l1 - mx), e2 = expf(l2 - mx);
    float s = e0 + e1 + e2;
    control[b * 3 + 0] = e0 / s;
    control[b * 3 + 1] = e1 / s;
    control[b * 3 + 2] = e2 / s;
  }
}

// ---------------- complex NT GEMM: C[b,m,s,o] = A @ W[m]^T (complex) ----------------
// a_bmsd=0: A rows dense (B*S, D).  a_bmsd=1: A row (b,s) lives at ((b*M+m)*S+s)*D.
__global__ void k_gemm_cplx(const float* __restrict__ Ar, const float* __restrict__ Ai,
                            const float* __restrict__ Wr, const float* __restrict__ Wi,
                            float* __restrict__ Cr, float* __restrict__ Ci, int a_bmsd) {
  __shared__ float sAr[GK][GT + 1], sAi[GK][GT + 1], sWr[GK][GT + 1], sWi[GK][GT + 1];
  int m = blockIdx.z;
  int row_blk = blockIdx.y * GT, o_blk = blockIdx.x * GT;
  const float* Wrm = Wr + (size_t)m * DD * DD;
  const float* Wim = Wi + (size_t)m * DD * DD;
  int tid = threadIdx.x;
  int kk = tid & 15, rr = tid >> 4;
  int ty = tid >> 4, tx = tid & 15;
  float accr[4][4] = {}, acci[4][4] = {};
  for (int k0 = 0; k0 < DD; k0 += GK) {
#pragma unroll
    for (int i = 0; i < 4; i++) {
      int row = rr + i * 16;
      int gr = row_blk + row;
      int b = gr >> 7, s = gr & (SS - 1);
      size_t aoff = a_bmsd ? ((size_t)((b * MM + m) * SS + s)) * DD : (size_t)gr * DD;
      sAr[kk][row] = Ar[aoff + k0 + kk];
      sAi[kk][row] = Ai[aoff + k0 + kk];
      int o = o_blk + row;
      sWr[kk][row] = Wrm[(size_t)o * DD + k0 + kk];
      sWi[kk][row] = Wim[(size_t)o * DD + k0 + kk];
    }
    __syncthreads();
#pragma unroll
    for (int k = 0; k < GK; k++) {
      float ar[4], ai[4], wr[4], wi[4];
#pragma unroll
      for (int i = 0; i < 4; i++) {
        ar[i] = sAr[k][ty + 16 * i];
        ai[i] = sAi[k][ty + 16 * i];
        wr[i] = sWr[k][tx + 16 * i];
        wi[i] = sWi[k][tx + 16 * i];
      }
#pragma unroll
      for (int i = 0; i < 4; i++)
#pragma unroll
        for (int j = 0; j < 4; j++) {
          accr[i][j] += ar[i] * wr[j] - ai[i] * wi[j];
          acci[i][j] += ai[i] * wr[j] + ar[i] * wi[j];
        }
    }
    __syncthreads();
  }
#pragma unroll
  for (int i = 0; i < 4; i++) {
    int gr = row_blk + ty + 16 * i;
    int b = gr >> 7, s = gr & (SS - 1);
    size_t coff = ((size_t)((b * MM + m) * SS + s)) * DD;
#pragma unroll
    for (int j = 0; j < 4; j++) {
      int o = o_blk + tx + 16 * j;
      Cr[coff + o] = accr[i][j];
      Ci[coff + o] = acci[i][j];
    }
  }
}

// ---------------- magnitude LN + phase renorm + mod scale (in place) ----------------
__global__ void k_lnphase(float* __restrict__ zr, float* __restrict__ zi,
                          const float* __restrict__ ln_scale, const float* __restrict__ ln_shift,
                          const float* __restrict__ mod_bias) {
  int row = blockIdx.x;            // (b*M+m)*S + s
  int m = (row >> 7) & (MM - 1);
  int tid = threadIdx.x;           // 128
  size_t base = (size_t)row * DD;
  float zrv[4], ziv[4], rv[4];
  float sum = 0.f, sumsq = 0.f;
#pragma unroll
  for (int i = 0; i < 4; i++) {
    int o = tid + i * 128;
    float a = zr[base + o], bv = zi[base + o];
    zrv[i] = a; ziv[i] = bv;
    float r = sqrtf(a * a + bv * bv);
    rv[i] = r;
    float mg = r + EPSF;
    sum += mg;
    sumsq += mg * mg;
  }
  __shared__ float rs[128], rq[128];
  rs[tid] = sum; rq[tid] = sumsq;
  __syncthreads();
  for (int off = 64; off > 0; off >>= 1) {
    if (tid < off) { rs[tid] += rs[tid + off]; rq[tid] += rq[tid + off]; }
    __syncthreads();
  }
  float mean = rs[0] * (1.0f / DD);
  float var = (rq[0] - (float)DD * mean * mean) * (1.0f / (DD - 1));
  float inv = 1.0f / sqrtf(var + EPSF);
#pragma unroll
  for (int i = 0; i < 4; i++) {
    int o = tid + i * 128;
    float mg = rv[i] + EPSF;
    float nm = (mg - mean) * inv * ln_scale[m * DD + o] + ln_shift[m * DD + o];
    float r = rv[i];
    float cosp, sinp;
    if (r > 0.f) { cosp = zrv[i] / r; sinp = ziv[i] / r; }
    else { cosp = 1.f; sinp = 0.f; }   // atan2(0,0)=0 -> cos=1, sin=0
    float z1r = nm * cosp, z1i = nm * sinp;
    float nrm = sqrtf(z1r * z1r + z1i * z1i) + EPSF;
    float sc = fmaxf(nrm + mod_bias[m * DD + o], 0.f) / nrm;
    zr[base + o] = z1r * sc;
    zi[base + o] = z1i * sc;
  }
}

// ---------------- scores = (qr.kr + qi.ki) * SCALE ----------------
__global__ void k_scores(const float* __restrict__ qr, const float* __restrict__ qi,
                         const float* __restrict__ kr, const float* __restrict__ ki,
                         float* __restrict__ scores) {
  __shared__ float sQr[GK][GT + 1], sQi[GK][GT + 1], sKr[GK][GT + 1], sKi[GK][GT + 1];
  int bm = blockIdx.z;
  int s_blk = blockIdx.y * GT, t_blk = blockIdx.x * GT;
  size_t base = (size_t)bm * SS * DD;
  int tid = threadIdx.x;
  int kkk = tid & 15, rr = tid >> 4;
  int ty = rr, tx = kkk;
  float acc[4][4] = {};
  for (int k0 = 0; k0 < DD; k0 += GK) {
#pragma unroll
    for (int i = 0; i < 4; i++) {
      int r = rr + i * 16;
      sQr[kkk][r] = qr[base + (size_t)(s_blk + r) * DD + k0 + kkk];
      sQi[kkk][r] = qi[base + (size_t)(s_blk + r) * DD + k0 + kkk];
      sKr[kkk][r] = kr[base + (size_t)(t_blk + r) * DD + k0 + kkk];
      sKi[kkk][r] = ki[base + (size_t)(t_blk + r) * DD + k0 + kkk];
    }
    __syncthreads();
#pragma unroll
    for (int k = 0; k < GK; k++) {
      float a0[4], a1[4], b0[4], b1[4];
#pragma unroll
      for (int i = 0; i < 4; i++) {
        a0[i] = sQr[k][ty + 16 * i];
        a1[i] = sQi[k][ty + 16 * i];
        b0[i] = sKr[k][tx + 16 * i];
        b1[i] = sKi[k][tx + 16 * i];
      }
#pragma unroll
      for (int i = 0; i < 4; i++)
#pragma unroll
        for (int j = 0; j < 4; j++)
          acc[i][j] += a0[i] * b0[j] + a1[i] * b1[j];
    }
    __syncthreads();
  }
#pragma unroll
  for (int i = 0; i < 4; i++) {
    int s = s_blk + ty + 16 * i;
#pragma unroll
    for (int j = 0; j < 4; j++) {
      int t = t_blk + tx + 16 * j;
      scores[((size_t)bm * SS + s) * SS + t] = acc[i][j] * SCALEF;
    }
  }
}

// ---------------- row softmax over t (in place) ----------------
__global__ void k_softmax(float* __restrict__ scores) {
  int row = blockIdx.x;
  int tid = threadIdx.x;  // 128
  __shared__ float buf[128];
  size_t base = (size_t)row * SS;
  float v = scores[base + tid];
  buf[tid] = v;
  __syncthreads();
  for (int off = 64; off > 0; off >>= 1) {
    if (tid < off) buf[tid] = fmaxf(buf[tid], buf[tid + off]);
    __syncthreads();
  }
  float mx = buf[0];
  __syncthreads();
  float e = expf(v - mx);
  buf[tid] = e;
  __syncthreads();
  for (int off = 64; off > 0; off >>= 1) {
    if (tid < off) buf[tid] += buf[tid + off];
    __syncthreads();
  }
  float s = buf[0];
  scores[base + tid] = e / s;
}

// ---------------- AV + gate + score/conf/halt heads ----------------
__global__ void k_attnav(const float* __restrict__ attn, const float* __restrict__ vr,
                         const float* __restrict__ vi, const float* __restrict__ gate_mask,
                         const float* __restrict__ score_w, const float* __restrict__ score_b,
                         const float* __restrict__ conf_w, const float* __restrict__ conf_b,
                         const float* __restrict__ halt_w, const float* __restrict__ halt_b,
                         float* __restrict__ pr, float* __restrict__ pi,
                         float* __restrict__ score, float* __restrict__ conf,
                         float* __restrict__ halt) {
  int row = blockIdx.x;           // (b*M+m)*S + s
  int bm = row >> 7;
  int m = bm & (MM - 1);
  int tid = threadIdx.x;          // 256
  __shared__ float att[SS];
  __shared__ float r0[256], r1[256], r2[256];
  if (tid < SS) att[tid] = attn[(size_t)row * SS + tid];
  __syncthreads();
  size_t vbase = (size_t)bm * SS * DD;
  float sp = 0.f, cp = 0.f, hp = 0.f;
#pragma unroll
  for (int i = 0; i < 2; i++) {
    int d = tid + i * 256;
    float aR = 0.f, aI = 0.f;
    for (int t = 0; t < SS; t++) {
      float a = att[t];
      aR += a * vr[vbase + (size_t)t * DD + d];
      aI += a * vi[vbase + (size_t)t * DD + d];
    }
    float g = 1.f / (1.f + expf(-gate_mask[m * DD + d]));
    float pR = aR * g, pI = aI * g;
    pr[(size_t)row * DD + d] = pR;
    pi[(size_t)row * DD + d] = pI;
    sp += pR * score_w[m * 2 * DD + d] + pI * score_w[m * 2 * DD + DD + d];
    cp += pR * conf_w[m * 2 * DD + d] + pI * conf_w[m * 2 * DD + DD + d];
    hp += pR * halt_w[m * 2 * DD + d] + pI * halt_w[m * 2 * DD + DD + d];
  }
  r0[tid] = sp; r1[tid] = cp; r2[tid] = hp;
  __syncthreads();
  for (int off = 128; off > 0; off >>= 1) {
    if (tid < off) { r0[tid] += r0[tid + off]; r1[tid] += r1[tid + off]; r2[tid] += r2[tid + off]; }
    __syncthreads();
  }
  if (tid == 0) {
    score[row] = r0[0] + score_b[m];
    conf[row] = 1.f / (1.f + expf(-(r1[0] + conf_b[m])));
    halt[row] = r2[0] + halt_b[m];
  }
}

// ---------------- stack update (per b) ----------------
__global__ void k_stack(const float* __restrict__ flat_in, const float* __restrict__ control,
                        float* __restrict__ memv, float* __restrict__ ptrv,
                        const float* __restrict__ st_score_w, const float* __restrict__ st_score_b,
                        const float* __restrict__ st_conf_w, const float* __restrict__ st_conf_b,
                        float* __restrict__ readv, float* __restrict__ stv) {
  int b = blockIdx.x;
  int tid = threadIdx.x;  // 256
  __shared__ float nptr[KK], wm[KK], ctrl[3];
  __shared__ float red[256], red2[256];
  if (tid < 3) ctrl[tid] = control[b * 3 + tid];
  __syncthreads();
  if (tid < KK) {
    int k = tid;
    float up = ptrv[b * KK + ((k + KK - 1) & (KK - 1))];
    float dn = ptrv[b * KK + ((k + 1) & (KK - 1))];
    float cu = ptrv[b * KK + k];
    nptr[k] = ctrl[0] * up + ctrl[1] * dn + ctrl[2] * cu;
    wm[k] = ctrl[0] * up;
  }
  __syncthreads();
  if (tid == 0) {
    float s = 0.f;
    for (int k = 0; k < KK; k++) s += nptr[k];
    float f = 1.f / (s + EPSF);
    for (int k = 0; k < KK; k++) nptr[k] *= f;
  }
  __syncthreads();
  if (tid < KK) ptrv[b * KK + tid] = nptr[tid];
  float ds = 0.f, dc = 0.f;
#pragma unroll
  for (int i = 0; i < 4; i++) {
    int e = tid + i * 256;
    float fl = flat_in[b * 2 * DD + e];
    float racc = 0.f;
    for (int k = 0; k < KK; k++) {
      size_t idx = ((size_t)(b * KK + k)) * 2 * DD + e;
      float nm = wm[k] * fl + memv[idx] * (1.f - wm[k]);
      memv[idx] = nm;
      racc += nm * nptr[k];
    }
    readv[b * 2 * DD + e] = racc;
    ds += racc * st_score_w[e];
    dc += racc * st_conf_w[e];
  }
  red[tid] = ds; red2[tid] = dc;
  __syncthreads();
  for (int off = 128; off > 0; off >>= 1) {
    if (tid < off) { red[tid] += red[tid + off]; red2[tid] += red2[tid + off]; }
    __syncthreads();
  }
  if (tid == 0) {
    stv[b] = red[0] + st_score_b[0];
    stv[BB + b] = 1.f / (1.f + expf(-(red2[0] + st_conf_b[0])));
  }
}

// ---------------- p = mean sigmoid(halt); coeff = p*rem; rem *= 1-p ----------------
__global__ void k_haltp(const float* __restrict__ halt, float* __restrict__ rem,
                        float* __restrict__ coeff) {
  int b = blockIdx.x;
  int tid = threadIdx.x;  // 256
  __shared__ float red[256];
  float v0 = halt[b * MM * SS + tid];
  float v1 = halt[b * MM * SS + 256 + tid];
  red[tid] = 1.f / (1.f + expf(-v0)) + 1.f / (1.f + expf(-v1));
  __syncthreads();
  for (int off = 128; off > 0; off >>= 1) {
    if (tid < off) red[tid] += red[tid + off];
    __syncthreads();
  }
  if (tid == 0) {
    float p = red[0] * (1.0f / (MM * SS));
    float r = rem[b];
    coeff[b] = p * r;
    rem[b] = r * (1.f - p);
  }
}

// ---------------- module-mix softmax + new state + acc update ----------------
__global__ void k_combine(const float* __restrict__ pr, const float* __restrict__ pi,
                          const float* __restrict__ score, const float* __restrict__ conf,
                          const float* __restrict__ stv, const float* __restrict__ readv,
                          const float* __restrict__ coeff,
                          float* __restrict__ sr, float* __restrict__ si, float* __restrict__ acc) {
  int bs = blockIdx.x;             // b*S + s
  int b = bs >> 7, s = bs & (SS - 1);
  int tid = threadIdx.x;           // 256
  __shared__ float w[5];
  if (tid == 0) {
    float l[5];
    for (int m = 0; m < MM; m++) {
      int r = (b * MM + m) * SS + s;
      l[m] = score[r] * conf[r];
    }
    l[4] = stv[b] * stv[BB + b];
    float mx = l[0];
    for (int j = 1; j < 5; j++) mx = fmaxf(mx, l[j]);
    float sum = 0.f;
    for (int j = 0; j < 5; j++) { l[j] = expf(l[j] - mx); sum += l[j]; }
    for (int j = 0; j < 5; j++) w[j] = l[j] / sum;
  }
  __syncthreads();
  float cf = coeff[b];
#pragma unroll
  for (int i = 0; i < 2; i++) {
    int d = tid + i * 256;
    float nsr = w[4] * readv[b * 2 * DD + d];
    float nsi = w[4] * readv[b * 2 * DD + DD + d];
#pragma unroll
    for (int m = 0; m < MM; m++) {
      size_t off = ((size_t)((b * MM + m) * SS + s)) * DD + d;
      nsr += w[m] * pr[off];
      nsi += w[m] * pi[off];
    }
    sr[(size_t)bs * DD + d] = nsr;
    si[(size_t)bs * DD + d] = nsi;
    size_t aoff = (size_t)bs * 2 * DD;
    acc[aoff + d] += cf * nsr;
    acc[aoff + DD + d] += cf * nsi;
  }
}

// ---------------- out = acc + rem * concat(sr, si) ----------------
__global__ void k_final(const float* __restrict__ acc, const float* __restrict__ rem,
                        const float* __restrict__ sr, const float* __restrict__ si,
                        float* __restrict__ out) {
  int idx = blockIdx.x * 256 + threadIdx.x;  // < B*S*2D
  int e = idx & (2 * DD - 1);
  int bs = idx >> 10;
  int b = bs >> 7;
  float v = (e < DD) ? sr[(size_t)bs * DD + e] : si[(size_t)bs * DD + e - DD];
  out[idx] = acc[idx] + rem[b] * v;
}

extern "C" void kernel_launch(void* const* d_in, const int* in_sizes, int n_in,
                              void* d_out, int out_size, void* d_ws, size_t ws_size,
                              hipStream_t stream) {
  const float* xr = (const float*)d_in[0];
  const float* xi = (const float*)d_in[1];
  const float* Wl_r = (const float*)d_in[2];
  const float* Wl_i = (const float*)d_in[3];
  const float* Wq_r = (const float*)d_in[4];
  const float* Wq_i = (const float*)d_in[5];
  const float* Wk_r = (const float*)d_in[6];
  const float* Wk_i = (const float*)d_in[7];
  const float* Wv_r = (const float*)d_in[8];
  const float* Wv_i = (const float*)d_in[9];
  const float* ln_scale = (const float*)d_in[10];
  const float* ln_shift = (const float*)d_in[11];
  const float* mod_bias = (const float*)d_in[12];
  const float* gate_mask = (const float*)d_in[13];
  const float* score_w = (const float*)d_in[14];
  const float* score_b = (const float*)d_in[15];
  const float* conf_w = (const float*)d_in[16];
  const float* conf_b = (const float*)d_in[17];
  const float* halt_w = (const float*)d_in[18];
  const float* halt_b = (const float*)d_in[19];
  const float* ctrl_w = (const float*)d_in[20];
  const float* ctrl_b = (const float*)d_in[21];
  const float* st_score_w = (const float*)d_in[22];
  const float* st_score_b = (const float*)d_in[23];
  const float* st_conf_w = (const float*)d_in[24];
  const float* st_conf_b = (const float*)d_in[25];
  float* out = (float*)d_out;

  const int BSD = BB * SS * DD;        // 262144
  const int BMSD = BB * MM * SS * DD;  // 1048576

  float* p = (float*)d_ws;
  float* sr = p; p += BSD;
  float* si = p; p += BSD;
  float* cr = p; p += BSD;
  float* ci = p; p += BSD;
  float* zr = p; p += BMSD;
  float* zi = p; p += BMSD;
  float* qr = p; p += BMSD;
  float* qi = p; p += BMSD;
  float* kr = p; p += BMSD;
  float* ki = p; p += BMSD;
  float* vr = p; p += BMSD;
  float* vi = p; p += BMSD;
  float* prb = p; p += BMSD;
  float* pib = p; p += BMSD;
  float* scoresb = p; p += BB * MM * SS * SS;  // 262144
  float* scorev = p; p += BB * MM * SS;
  float* confv = p; p += BB * MM * SS;
  float* haltv = p; p += BB * MM * SS;
  float* flat = p; p += BB * 2 * DD;
  float* control = p; p += 16;
  float* memv = p; p += BB * KK * 2 * DD;
  float* ptrv = p; p += BB * KK;
  float* readv = p; p += BB * 2 * DD;
  float* stv = p; p += 2 * BB;
  float* accb = p; p += BB * SS * 2 * DD;  // 524288
  float* rem = p; p += BB;
  float* coeff = p; p += BB;

  k_init<<<2048, 256, 0, stream>>>(xr, xi, sr, si, accb, memv, ptrv, rem);

  for (int step = 0; step < NSTEPS; ++step) {
    k_prep<<<BSD / 256, 256, 0, stream>>>(xr, xi, sr, si, cr, ci);
    k_flatctrl<<<BB, 256, 0, stream>>>(sr, si, ctrl_w, ctrl_b, flat, control);
    k_gemm_cplx<<<dim3(DD / GT, (BB * SS) / GT, MM), 256, 0, stream>>>(cr, ci, Wl_r, Wl_i, zr, zi, 0);
    k_lnphase<<<BB * MM * SS, 128, 0, stream>>>(zr, zi, ln_scale, ln_shift, mod_bias);
    k_gemm_cplx<<<dim3(DD / GT, (BB * SS) / GT, MM), 256, 0, stream>>>(zr, zi, Wq_r, Wq_i, qr, qi, 1);
    k_gemm_cplx<<<dim3(DD / GT, (BB * SS) / GT, MM), 256, 0, stream>>>(zr, zi, Wk_r, Wk_i, kr, ki, 1);
    k_gemm_cplx<<<dim3(DD / GT, (BB * SS) / GT, MM), 256, 0, stream>>>(zr, zi, Wv_r, Wv_i, vr, vi, 1);
    k_scores<<<dim3(SS / GT, SS / GT, BB * MM), 256, 0, stream>>>(qr, qi, kr, ki, scoresb);
    k_softmax<<<BB * MM * SS, 128, 0, stream>>>(scoresb);
    k_attnav<<<BB * MM * SS, 256, 0, stream>>>(scoresb, vr, vi, gate_mask, score_w, score_b,
                                               conf_w, conf_b, halt_w, halt_b,
                                               prb, pib, scorev, confv, haltv);
    k_stack<<<BB, 256, 0, stream>>>(flat, control, memv, ptrv, st_score_w, st_score_b,
                                    st_conf_w, st_conf_b, readv, stv);
    k_haltp<<<BB, 256, 0, stream>>>(haltv, rem, coeff);
    k_combine<<<BB * SS, 256, 0, stream>>>(prb, pib, scorev, confv, stv, readv, coeff, sr, si, accb);
  }

  k_final<<<(BB * SS * 2 * DD) / 256, 256, 0, stream>>>(accb, rem, sr, si, out);
}

// Round 3
// 9240.116 us; speedup vs baseline: 5.6082x; 5.6082x over previous
//
#include <hip/hip_runtime.h>

#define DD 512
#define MM 4
#define BB 4
#define SS 128
#define KK 32
#define NSTEPS 16
#define EPSF 1e-6f
#define SCALEF 0.04419417382415922f  // 512^-0.5

typedef unsigned short u16;
typedef __bf16 bf16x8 __attribute__((ext_vector_type(8)));
typedef u16 u16x8 __attribute__((ext_vector_type(8)));
typedef float f32x16 __attribute__((ext_vector_type(16)));

__device__ inline void split_bf16(float x, u16& h, u16& l) {
  __bf16 hb = (__bf16)x;
  float hf = (float)hb;
  __bf16 lb = (__bf16)(x - hf);
  h = __builtin_bit_cast(u16, hb);
  l = __builtin_bit_cast(u16, lb);
}

// ---------------- weight fp32 -> split bf16 [row][1024] (hi | lo) ----------------
__global__ void k_convw(const float* __restrict__ src, u16* __restrict__ dst) {
  int idx = blockIdx.x * 256 + threadIdx.x;  // over M*D*D = 1048576
  int row = idx >> 9, k = idx & 511;
  u16 h, l;
  split_bf16(src[idx], h, l);
  dst[(size_t)row * 1024 + k] = h;
  dst[(size_t)row * 1024 + 512 + k] = l;
}

// ---------------- init ----------------
__global__ void k_init(const float* __restrict__ xr, const float* __restrict__ xi,
                       float* __restrict__ sr, float* __restrict__ si,
                       float* __restrict__ acc, float* __restrict__ memv,
                       float* __restrict__ ptrv, float* __restrict__ rem) {
  int idx = blockIdx.x * 256 + threadIdx.x;
  if (idx < BB * SS * 2 * DD) acc[idx] = 0.f;
  if (idx < BB * SS * DD) { sr[idx] = xr[idx]; si[idx] = xi[idx]; }
  if (idx < BB * KK * 2 * DD) memv[idx] = 0.f;
  if (idx < BB * KK) ptrv[idx] = ((idx & (KK - 1)) == 0) ? 1.f : 0.f;
  if (idx < BB) rem[idx] = 1.f;
}

// ---------------- c = 0.5x + 0.5s -> split bf16 ----------------
__global__ void k_prep(const float* __restrict__ xr, const float* __restrict__ xi,
                       const float* __restrict__ sr, const float* __restrict__ si,
                       u16* __restrict__ crbf, u16* __restrict__ cibf) {
  int idx = blockIdx.x * 256 + threadIdx.x;  // < B*S*D
  int row = idx >> 9, d = idx & 511;
  float cr = 0.5f * xr[idx] + 0.5f * sr[idx];
  float ci = 0.5f * xi[idx] + 0.5f * si[idx];
  u16 h, l;
  split_bf16(cr, h, l);
  crbf[(size_t)row * 1024 + d] = h;
  crbf[(size_t)row * 1024 + 512 + d] = l;
  split_bf16(ci, h, l);
  cibf[(size_t)row * 1024 + d] = h;
  cibf[(size_t)row * 1024 + 512 + d] = l;
}

// ---------------- flat_in (mean over S) + control softmax ----------------
__global__ void k_flatctrl(const float* __restrict__ sr, const float* __restrict__ si,
                           const float* __restrict__ ctrl_w, const float* __restrict__ ctrl_b,
                           float* __restrict__ flat_in, float* __restrict__ control) {
  int b = blockIdx.x;
  int tid = threadIdx.x;  // 256
  __shared__ float red[3 * 256];
  float d0 = 0.f, d1 = 0.f, d2 = 0.f;
  for (int i = 0; i < 4; i++) {
    int e = tid + i * 256;  // 0..1023
    const float* basep = (e < DD) ? sr : si;
    int d = (e < DD) ? e : (e - DD);
    float sum = 0.f;
    int base = b * SS * DD + d;
    for (int s = 0; s < SS; s++) sum += basep[base + s * DD];
    float fv = sum * (1.0f / SS);
    flat_in[b * 2 * DD + e] = fv;
    d0 += fv * ctrl_w[e * 3 + 0];
    d1 += fv * ctrl_w[e * 3 + 1];
    d2 += fv * ctrl_w[e * 3 + 2];
  }
  red[tid] = d0; red[256 + tid] = d1; red[512 + tid] = d2;
  __syncthreads();
  for (int off = 128; off > 0; off >>= 1) {
    if (tid < off) {
      red[tid] += red[tid + off];
      red[256 + tid] += red[256 + tid + off];
      red[512 + tid] += red[512 + tid + off];
    }
    __syncthreads();
  }
  if (tid == 0) {
    float l0 = red[0] + ctrl_b[0], l1 = red[256] + ctrl_b[1], l2 = red[512] + ctrl_b[2];
    float mx = fmaxf(l0, fmaxf(l1, l2));
    float e0 = expf(l0 - mx), e1 = expf(l1 - mx), e2 = expf(l2 - mx);
    float s = e0 + e1 + e2;
    control[b * 3 + 0] = e0 / s;
    control[b * 3 + 1] = e1 / s;
    control[b * 3 + 2] = e2 / s;
  }
}

// ---------------- complex NT GEMM via 3-term split-bf16 MFMA ----------------
// x*y ~= xh*yh + xl*yh + xh*yl  (drop xl*yl ~ 2^-18)
// Storage: A rows [Ah(512) | Al(512)], W rows [Wh(512) | Wl(512)].
// Segments: seg0 A[0:512]*W[0:512], seg1 A[512:1024]*W[0:512], seg2 A[0:512]*W[512:1024].
// a_bmsd=0: A row = b*S+s (dense).  a_bmsd=1: A row = (b*M+m)*S+s.
#define LSTR 72  // LDS row stride in bf16 elems (16B aligned, non-pow2 banks)
__global__ __launch_bounds__(256) void k_gemm_mfma(
    const u16* __restrict__ Ar, const u16* __restrict__ Ai,
    const u16* __restrict__ Wr, const u16* __restrict__ Wi,
    float* __restrict__ Cr, float* __restrict__ Ci, int a_bmsd) {
  __shared__ u16 sAr[64][LSTR], sAi[64][LSTR], sWr[64][LSTR], sWi[64][LSTR];
  int m = blockIdx.z;
  int row_blk = blockIdx.y * 64, o_blk = blockIdx.x * 64;
  int tid = threadIdx.x;

  // staging indices: each thread loads 16B per (array, half)
  int lrow = tid >> 3;           // 0..31
  int lk8 = (tid & 7) << 3;      // 0..56
  int gr0 = row_blk + lrow, gr1 = gr0 + 32;
  size_t arow0, arow1;
  if (a_bmsd) {
    arow0 = (size_t)(((gr0 >> 7) * MM + m) * SS + (gr0 & (SS - 1)));
    arow1 = (size_t)(((gr1 >> 7) * MM + m) * SS + (gr1 & (SS - 1)));
  } else {
    arow0 = (size_t)gr0; arow1 = (size_t)gr1;
  }
  size_t wrow0 = (size_t)m * DD + o_blk + lrow;
  size_t wrow1 = wrow0 + 32;

  // compute indices
  int wave = tid >> 6, lane = tid & 63;
  int wrow = (wave >> 1) * 32, wcol = (wave & 1) * 32;
  int l31 = lane & 31, khalf = (lane >> 5) * 8;

  f32x16 accP, accN, accI;
  for (int i = 0; i < 16; i++) { accP[i] = 0.f; accN[i] = 0.f; accI[i] = 0.f; }

  for (int it = 0; it < 24; ++it) {
    int seg = it >> 3;               // 0,1,2
    int k0 = (it & 7) * 64;          // 0..448
    int aofs = (seg == 1) ? 512 : 0; // A: lo half for seg1
    int wofs = (seg == 2) ? 512 : 0; // W: lo half for seg2
    u16x8 ar0 = *(const u16x8*)&Ar[arow0 * 1024 + aofs + k0 + lk8];
    u16x8 ar1 = *(const u16x8*)&Ar[arow1 * 1024 + aofs + k0 + lk8];
    u16x8 ai0 = *(const u16x8*)&Ai[arow0 * 1024 + aofs + k0 + lk8];
    u16x8 ai1 = *(const u16x8*)&Ai[arow1 * 1024 + aofs + k0 + lk8];
    u16x8 wr0 = *(const u16x8*)&Wr[wrow0 * 1024 + wofs + k0 + lk8];
    u16x8 wr1 = *(const u16x8*)&Wr[wrow1 * 1024 + wofs + k0 + lk8];
    u16x8 wi0 = *(const u16x8*)&Wi[wrow0 * 1024 + wofs + k0 + lk8];
    u16x8 wi1 = *(const u16x8*)&Wi[wrow1 * 1024 + wofs + k0 + lk8];
    __syncthreads();  // previous iter's LDS reads done
    *(u16x8*)&sAr[lrow][lk8] = ar0;
    *(u16x8*)&sAr[lrow + 32][lk8] = ar1;
    *(u16x8*)&sAi[lrow][lk8] = ai0;
    *(u16x8*)&sAi[lrow + 32][lk8] = ai1;
    *(u16x8*)&sWr[lrow][lk8] = wr0;
    *(u16x8*)&sWr[lrow + 32][lk8] = wr1;
    *(u16x8*)&sWi[lrow][lk8] = wi0;
    *(u16x8*)&sWi[lrow + 32][lk8] = wi1;
    __syncthreads();
#pragma unroll
    for (int kk = 0; kk < 64; kk += 16) {
      bf16x8 fAr = *(const bf16x8*)&sAr[wrow + l31][kk + khalf];
      bf16x8 fAi = *(const bf16x8*)&sAi[wrow + l31][kk + khalf];
      bf16x8 fWr = *(const bf16x8*)&sWr[wcol + l31][kk + khalf];
      bf16x8 fWi = *(const bf16x8*)&sWi[wcol + l31][kk + khalf];
      accP = __builtin_amdgcn_mfma_f32_32x32x16_bf16(fAr, fWr, accP, 0, 0, 0);
      accN = __builtin_amdgcn_mfma_f32_32x32x16_bf16(fAi, fWi, accN, 0, 0, 0);
      accI = __builtin_amdgcn_mfma_f32_32x32x16_bf16(fAi, fWr, accI, 0, 0, 0);
      accI = __builtin_amdgcn_mfma_f32_32x32x16_bf16(fAr, fWi, accI, 0, 0, 0);
    }
  }

  int o = o_blk + wcol + l31;
#pragma unroll
  for (int reg = 0; reg < 16; reg++) {
    int r_in = (reg & 3) + 8 * (reg >> 2) + 4 * (lane >> 5);
    int gr = row_blk + wrow + r_in;
    int b = gr >> 7, s = gr & (SS - 1);
    size_t coff = ((size_t)((b * MM + m) * SS + s)) * DD + o;
    Cr[coff] = accP[reg] - accN[reg];
    Ci[coff] = accI[reg];
  }
}

// ---------------- magnitude LN + phase renorm + mod scale -> split bf16 ----------------
__global__ void k_lnphase(const float* __restrict__ zr, const float* __restrict__ zi,
                          const float* __restrict__ ln_scale, const float* __restrict__ ln_shift,
                          const float* __restrict__ mod_bias,
                          u16* __restrict__ zbr, u16* __restrict__ zbi) {
  int row = blockIdx.x;            // (b*M+m)*S + s
  int m = (row >> 7) & (MM - 1);
  int tid = threadIdx.x;           // 128
  size_t base = (size_t)row * DD;
  float zrv[4], ziv[4], rv[4];
  float sum = 0.f, sumsq = 0.f;
#pragma unroll
  for (int i = 0; i < 4; i++) {
    int o = tid + i * 128;
    float a = zr[base + o], bv = zi[base + o];
    zrv[i] = a; ziv[i] = bv;
    float r = sqrtf(a * a + bv * bv);
    rv[i] = r;
    float mg = r + EPSF;
    sum += mg;
    sumsq += mg * mg;
  }
  __shared__ float rs[128], rq[128];
  rs[tid] = sum; rq[tid] = sumsq;
  __syncthreads();
  for (int off = 64; off > 0; off >>= 1) {
    if (tid < off) { rs[tid] += rs[tid + off]; rq[tid] += rq[tid + off]; }
    __syncthreads();
  }
  float mean = rs[0] * (1.0f / DD);
  float var = (rq[0] - (float)DD * mean * mean) * (1.0f / (DD - 1));
  float inv = 1.0f / sqrtf(var + EPSF);
#pragma unroll
  for (int i = 0; i < 4; i++) {
    int o = tid + i * 128;
    float mg = rv[i] + EPSF;
    float nm = (mg - mean) * inv * ln_scale[m * DD + o] + ln_shift[m * DD + o];
    float r = rv[i];
    float cosp, sinp;
    if (r > 0.f) { cosp = zrv[i] / r; sinp = ziv[i] / r; }
    else { cosp = 1.f; sinp = 0.f; }
    float z1r = nm * cosp, z1i = nm * sinp;
    float nrm = sqrtf(z1r * z1r + z1i * z1i) + EPSF;
    float sc = fmaxf(nrm + mod_bias[m * DD + o], 0.f) / nrm;
    u16 h, l;
    split_bf16(z1r * sc, h, l);
    zbr[(size_t)row * 1024 + o] = h;
    zbr[(size_t)row * 1024 + 512 + o] = l;
    split_bf16(z1i * sc, h, l);
    zbi[(size_t)row * 1024 + o] = h;
    zbi[(size_t)row * 1024 + 512 + o] = l;
  }
}

// ---------------- scores = (qr.kr + qi.ki) * SCALE (fp32 tiled) ----------------
#define GT 64
#define GK 16
__global__ void k_scores(const float* __restrict__ qr, const float* __restrict__ qi,
                         const float* __restrict__ kr, const float* __restrict__ ki,
                         float* __restrict__ scores) {
  __shared__ float sQr[GK][GT + 1], sQi[GK][GT + 1], sKr[GK][GT + 1], sKi[GK][GT + 1];
  int bm = blockIdx.z;
  int s_blk = blockIdx.y * GT, t_blk = blockIdx.x * GT;
  size_t base = (size_t)bm * SS * DD;
  int tid = threadIdx.x;
  int kkk = tid & 15, rr = tid >> 4;
  int ty = rr, tx = kkk;
  float acc[4][4] = {};
  for (int k0 = 0; k0 < DD; k0 += GK) {
#pragma unroll
    for (int i = 0; i < 4; i++) {
      int r = rr + i * 16;
      sQr[kkk][r] = qr[base + (size_t)(s_blk + r) * DD + k0 + kkk];
      sQi[kkk][r] = qi[base + (size_t)(s_blk + r) * DD + k0 + kkk];
      sKr[kkk][r] = kr[base + (size_t)(t_blk + r) * DD + k0 + kkk];
      sKi[kkk][r] = ki[base + (size_t)(t_blk + r) * DD + k0 + kkk];
    }
    __syncthreads();
#pragma unroll
    for (int k = 0; k < GK; k++) {
      float a0[4], a1[4], b0[4], b1[4];
#pragma unroll
      for (int i = 0; i < 4; i++) {
        a0[i] = sQr[k][ty + 16 * i];
        a1[i] = sQi[k][ty + 16 * i];
        b0[i] = sKr[k][tx + 16 * i];
        b1[i] = sKi[k][tx + 16 * i];
      }
#pragma unroll
      for (int i = 0; i < 4; i++)
#pragma unroll
        for (int j = 0; j < 4; j++)
          acc[i][j] += a0[i] * b0[j] + a1[i] * b1[j];
    }
    __syncthreads();
  }
#pragma unroll
  for (int i = 0; i < 4; i++) {
    int s = s_blk + ty + 16 * i;
#pragma unroll
    for (int j = 0; j < 4; j++) {
      int t = t_blk + tx + 16 * j;
      scores[((size_t)bm * SS + s) * SS + t] = acc[i][j] * SCALEF;
    }
  }
}

// ---------------- row softmax over t (in place) ----------------
__global__ void k_softmax(float* __restrict__ scores) {
  int row = blockIdx.x;
  int tid = threadIdx.x;  // 128
  __shared__ float buf[128];
  size_t base = (size_t)row * SS;
  float v = scores[base + tid];
  buf[tid] = v;
  __syncthreads();
  for (int off = 64; off > 0; off >>= 1) {
    if (tid < off) buf[tid] = fmaxf(buf[tid], buf[tid + off]);
    __syncthreads();
  }
  float mx = buf[0];
  __syncthreads();
  float e = expf(v - mx);
  buf[tid] = e;
  __syncthreads();
  for (int off = 64; off > 0; off >>= 1) {
    if (tid < off) buf[tid] += buf[tid + off];
    __syncthreads();
  }
  float s = buf[0];
  scores[base + tid] = e / s;
}

// ---------------- AV + gate + score/conf/halt heads ----------------
__global__ void k_attnav(const float* __restrict__ attn, const float* __restrict__ vr,
                         const float* __restrict__ vi, const float* __restrict__ gate_mask,
                         const float* __restrict__ score_w, const float* __restrict__ score_b,
                         const float* __restrict__ conf_w, const float* __restrict__ conf_b,
                         const float* __restrict__ halt_w, const float* __restrict__ halt_b,
                         float* __restrict__ pr, float* __restrict__ pi,
                         float* __restrict__ score, float* __restrict__ conf,
                         float* __restrict__ halt) {
  int row = blockIdx.x;           // (b*M+m)*S + s
  int bm = row >> 7;
  int m = bm & (MM - 1);
  int tid = threadIdx.x;          // 256
  __shared__ float att[SS];
  __shared__ float r0[256], r1[256], r2[256];
  if (tid < SS) att[tid] = attn[(size_t)row * SS + tid];
  __syncthreads();
  size_t vbase = (size_t)bm * SS * DD;
  float sp = 0.f, cp = 0.f, hp = 0.f;
#pragma unroll
  for (int i = 0; i < 2; i++) {
    int d = tid + i * 256;
    float aR = 0.f, aI = 0.f;
    for (int t = 0; t < SS; t++) {
      float a = att[t];
      aR += a * vr[vbase + (size_t)t * DD + d];
      aI += a * vi[vbase + (size_t)t * DD + d];
    }
    float g = 1.f / (1.f + expf(-gate_mask[m * DD + d]));
    float pR = aR * g, pI = aI * g;
    pr[(size_t)row * DD + d] = pR;
    pi[(size_t)row * DD + d] = pI;
    sp += pR * score_w[m * 2 * DD + d] + pI * score_w[m * 2 * DD + DD + d];
    cp += pR * conf_w[m * 2 * DD + d] + pI * conf_w[m * 2 * DD + DD + d];
    hp += pR * halt_w[m * 2 * DD + d] + pI * halt_w[m * 2 * DD + DD + d];
  }
  r0[tid] = sp; r1[tid] = cp; r2[tid] = hp;
  __syncthreads();
  for (int off = 128; off > 0; off >>= 1) {
    if (tid < off) { r0[tid] += r0[tid + off]; r1[tid] += r1[tid + off]; r2[tid] += r2[tid + off]; }
    __syncthreads();
  }
  if (tid == 0) {
    score[row] = r0[0] + score_b[m];
    conf[row] = 1.f / (1.f + expf(-(r1[0] + conf_b[m])));
    halt[row] = r2[0] + halt_b[m];
  }
}

// ---------------- stack update (per b) ----------------
__global__ void k_stack(const float* __restrict__ flat_in, const float* __restrict__ control,
                        float* __restrict__ memv, float* __restrict__ ptrv,
                        const float* __restrict__ st_score_w, const float* __restrict__ st_score_b,
                        const float* __restrict__ st_conf_w, const float* __restrict__ st_conf_b,
                        float* __restrict__ readv, float* __restrict__ stv) {
  int b = blockIdx.x;
  int tid = threadIdx.x;  // 256
  __shared__ float nptr[KK], wm[KK], ctrl[3];
  __shared__ float red[256], red2[256];
  if (tid < 3) ctrl[tid] = control[b * 3 + tid];
  __syncthreads();
  if (tid < KK) {
    int k = tid;
    float up = ptrv[b * KK + ((k + KK - 1) & (KK - 1))];
    float dn = ptrv[b * KK + ((k + 1) & (KK - 1))];
    float cu = ptrv[b * KK + k];
    nptr[k] = ctrl[0] * up + ctrl[1] * dn + ctrl[2] * cu;
    wm[k] = ctrl[0] * up;
  }
  __syncthreads();
  if (tid == 0) {
    float s = 0.f;
    for (int k = 0; k < KK; k++) s += nptr[k];
    float f = 1.f / (s + EPSF);
    for (int k = 0; k < KK; k++) nptr[k] *= f;
  }
  __syncthreads();
  if (tid < KK) ptrv[b * KK + tid] = nptr[tid];
  float ds = 0.f, dc = 0.f;
#pragma unroll
  for (int i = 0; i < 4; i++) {
    int e = tid + i * 256;
    float fl = flat_in[b * 2 * DD + e];
    float racc = 0.f;
    for (int k = 0; k < KK; k++) {
      size_t idx = ((size_t)(b * KK + k)) * 2 * DD + e;
      float nm = wm[k] * fl + memv[idx] * (1.f - wm[k]);
      memv[idx] = nm;
      racc += nm * nptr[k];
    }
    readv[b * 2 * DD + e] = racc;
    ds += racc * st_score_w[e];
    dc += racc * st_conf_w[e];
  }
  red[tid] = ds; red2[tid] = dc;
  __syncthreads();
  for (int off = 128; off > 0; off >>= 1) {
    if (tid < off) { red[tid] += red[tid + off]; red2[tid] += red2[tid + off]; }
    __syncthreads();
  }
  if (tid == 0) {
    stv[b] = red[0] + st_score_b[0];
    stv[BB + b] = 1.f / (1.f + expf(-(red2[0] + st_conf_b[0])));
  }
}

// ---------------- p = mean sigmoid(halt); coeff = p*rem; rem *= 1-p ----------------
__global__ void k_haltp(const float* __restrict__ halt, float* __restrict__ rem,
                        float* __restrict__ coeff) {
  int b = blockIdx.x;
  int tid = threadIdx.x;  // 256
  __shared__ float red[256];
  float v0 = halt[b * MM * SS + tid];
  float v1 = halt[b * MM * SS + 256 + tid];
  red[tid] = 1.f / (1.f + expf(-v0)) + 1.f / (1.f + expf(-v1));
  __syncthreads();
  for (int off = 128; off > 0; off >>= 1) {
    if (tid < off) red[tid] += red[tid + off];
    __syncthreads();
  }
  if (tid == 0) {
    float p = red[0] * (1.0f / (MM * SS));
    float r = rem[b];
    coeff[b] = p * r;
    rem[b] = r * (1.f - p);
  }
}

// ---------------- module-mix softmax + new state + acc update ----------------
__global__ void k_combine(const float* __restrict__ pr, const float* __restrict__ pi,
                          const float* __restrict__ score, const float* __restrict__ conf,
                          const float* __restrict__ stv, const float* __restrict__ readv,
                          const float* __restrict__ coeff,
                          float* __restrict__ sr, float* __restrict__ si, float* __restrict__ acc) {
  int bs = blockIdx.x;             // b*S + s
  int b = bs >> 7, s = bs & (SS - 1);
  int tid = threadIdx.x;           // 256
  __shared__ float w[5];
  if (tid == 0) {
    float l[5];
    for (int m = 0; m < MM; m++) {
      int r = (b * MM + m) * SS + s;
      l[m] = score[r] * conf[r];
    }
    l[4] = stv[b] * stv[BB + b];
    float mx = l[0];
    for (int j = 1; j < 5; j++) mx = fmaxf(mx, l[j]);
    float sum = 0.f;
    for (int j = 0; j < 5; j++) { l[j] = expf(l[j] - mx); sum += l[j]; }
    for (int j = 0; j < 5; j++) w[j] = l[j] / sum;
  }
  __syncthreads();
  float cf = coeff[b];
#pragma unroll
  for (int i = 0; i < 2; i++) {
    int d = tid + i * 256;
    float nsr = w[4] * readv[b * 2 * DD + d];
    float nsi = w[4] * readv[b * 2 * DD + DD + d];
#pragma unroll
    for (int m = 0; m < MM; m++) {
      size_t off = ((size_t)((b * MM + m) * SS + s)) * DD + d;
      nsr += w[m] * pr[off];
      nsi += w[m] * pi[off];
    }
    sr[(size_t)bs * DD + d] = nsr;
    si[(size_t)bs * DD + d] = nsi;
    size_t aoff = (size_t)bs * 2 * DD;
    acc[aoff + d] += cf * nsr;
    acc[aoff + DD + d] += cf * nsi;
  }
}

// ---------------- out = acc + rem * concat(sr, si) ----------------
__global__ void k_final(const float* __restrict__ acc, const float* __restrict__ rem,
                        const float* __restrict__ sr, const float* __restrict__ si,
                        float* __restrict__ out) {
  int idx = blockIdx.x * 256 + threadIdx.x;  // < B*S*2D
  int e = idx & (2 * DD - 1);
  int bs = idx >> 10;
  int b = bs >> 7;
  float v = (e < DD) ? sr[(size_t)bs * DD + e] : si[(size_t)bs * DD + e - DD];
  out[idx] = acc[idx] + rem[b] * v;
}

extern "C" void kernel_launch(void* const* d_in, const int* in_sizes, int n_in,
                              void* d_out, int out_size, void* d_ws, size_t ws_size,
                              hipStream_t stream) {
  const float* xr = (const float*)d_in[0];
  const float* xi = (const float*)d_in[1];
  const float* Wl_r = (const float*)d_in[2];
  const float* Wl_i = (const float*)d_in[3];
  const float* Wq_r = (const float*)d_in[4];
  const float* Wq_i = (const float*)d_in[5];
  const float* Wk_r = (const float*)d_in[6];
  const float* Wk_i = (const float*)d_in[7];
  const float* Wv_r = (const float*)d_in[8];
  const float* Wv_i = (const float*)d_in[9];
  const float* ln_scale = (const float*)d_in[10];
  const float* ln_shift = (const float*)d_in[11];
  const float* mod_bias = (const float*)d_in[12];
  const float* gate_mask = (const float*)d_in[13];
  const float* score_w = (const float*)d_in[14];
  const float* score_b = (const float*)d_in[15];
  const float* conf_w = (const float*)d_in[16];
  const float* conf_b = (const float*)d_in[17];
  const float* halt_w = (const float*)d_in[18];
  const float* halt_b = (const float*)d_in[19];
  const float* ctrl_w = (const float*)d_in[20];
  const float* ctrl_b = (const float*)d_in[21];
  const float* st_score_w = (const float*)d_in[22];
  const float* st_score_b = (const float*)d_in[23];
  const float* st_conf_w = (const float*)d_in[24];
  const float* st_conf_b = (const float*)d_in[25];
  float* out = (float*)d_out;

  const int BSD = BB * SS * DD;        // 262144
  const int BMSD = BB * MM * SS * DD;  // 1048576
  const size_t WSLOT = (size_t)MM * DD * 1024;  // 2097152 u16 per weight matrix

  char* pc = (char*)d_ws;
  float* sr = (float*)pc; pc += (size_t)BSD * 4;
  float* si = (float*)pc; pc += (size_t)BSD * 4;
  float* zr = (float*)pc; pc += (size_t)BMSD * 4;
  float* zi = (float*)pc; pc += (size_t)BMSD * 4;
  float* qr = (float*)pc; pc += (size_t)BMSD * 4;
  float* qi = (float*)pc; pc += (size_t)BMSD * 4;
  float* kr = (float*)pc; pc += (size_t)BMSD * 4;
  float* ki = (float*)pc; pc += (size_t)BMSD * 4;
  float* vr = (float*)pc; pc += (size_t)BMSD * 4;
  float* vi = (float*)pc; pc += (size_t)BMSD * 4;
  float* prb = (float*)pc; pc += (size_t)BMSD * 4;
  float* pib = (float*)pc; pc += (size_t)BMSD * 4;
  float* scoresb = (float*)pc; pc += (size_t)BB * MM * SS * SS * 4;
  float* scorev = (float*)pc; pc += (size_t)BB * MM * SS * 4;
  float* confv = (float*)pc; pc += (size_t)BB * MM * SS * 4;
  float* haltv = (float*)pc; pc += (size_t)BB * MM * SS * 4;
  float* flat = (float*)pc; pc += (size_t)BB * 2 * DD * 4;
  float* control = (float*)pc; pc += 64;
  float* memv = (float*)pc; pc += (size_t)BB * KK * 2 * DD * 4;
  float* ptrv = (float*)pc; pc += (size_t)BB * KK * 4;
  float* readv = (float*)pc; pc += (size_t)BB * 2 * DD * 4;
  float* stv = (float*)pc; pc += (size_t)2 * BB * 4;
  float* accb = (float*)pc; pc += (size_t)BB * SS * 2 * DD * 4;
  float* rem = (float*)pc; pc += (size_t)BB * 4;
  float* coeff = (float*)pc; pc += (size_t)BB * 4;
  u16* crbf = (u16*)pc; pc += (size_t)BB * SS * 1024 * 2;
  u16* cibf = (u16*)pc; pc += (size_t)BB * SS * 1024 * 2;
  u16* zbr = (u16*)pc; pc += (size_t)BB * MM * SS * 1024 * 2;
  u16* zbi = (u16*)pc; pc += (size_t)BB * MM * SS * 1024 * 2;
  u16* wbf = (u16*)pc; pc += 8 * WSLOT * 2;  // Wl_r,Wl_i,Wq_r,Wq_i,Wk_r,Wk_i,Wv_r,Wv_i

  // one-time (per launch) weight conversion: 8 matrices of 1M elems
  k_convw<<<4096, 256, 0, stream>>>(Wl_r, wbf + 0 * WSLOT);
  k_convw<<<4096, 256, 0, stream>>>(Wl_i, wbf + 1 * WSLOT);
  k_convw<<<4096, 256, 0, stream>>>(Wq_r, wbf + 2 * WSLOT);
  k_convw<<<4096, 256, 0, stream>>>(Wq_i, wbf + 3 * WSLOT);
  k_convw<<<4096, 256, 0, stream>>>(Wk_r, wbf + 4 * WSLOT);
  k_convw<<<4096, 256, 0, stream>>>(Wk_i, wbf + 5 * WSLOT);
  k_convw<<<4096, 256, 0, stream>>>(Wv_r, wbf + 6 * WSLOT);
  k_convw<<<4096, 256, 0, stream>>>(Wv_i, wbf + 7 * WSLOT);

  k_init<<<2048, 256, 0, stream>>>(xr, xi, sr, si, accb, memv, ptrv, rem);

  dim3 ggrid(DD / 64, (BB * SS) / 64, MM);  // (8, 8, 4)

  for (int step = 0; step < NSTEPS; ++step) {
    k_prep<<<BSD / 256, 256, 0, stream>>>(xr, xi, sr, si, crbf, cibf);
    k_flatctrl<<<BB, 256, 0, stream>>>(sr, si, ctrl_w, ctrl_b, flat, control);
    k_gemm_mfma<<<ggrid, 256, 0, stream>>>(crbf, cibf, wbf + 0 * WSLOT, wbf + 1 * WSLOT, zr, zi, 0);
    k_lnphase<<<BB * MM * SS, 128, 0, stream>>>(zr, zi, ln_scale, ln_shift, mod_bias, zbr, zbi);
    k_gemm_mfma<<<ggrid, 256, 0, stream>>>(zbr, zbi, wbf + 2 * WSLOT, wbf + 3 * WSLOT, qr, qi, 1);
    k_gemm_mfma<<<ggrid, 256, 0, stream>>>(zbr, zbi, wbf + 4 * WSLOT, wbf + 5 * WSLOT, kr, ki, 1);
    k_gemm_mfma<<<ggrid, 256, 0, stream>>>(zbr, zbi, wbf + 6 * WSLOT, wbf + 7 * WSLOT, vr, vi, 1);
    k_scores<<<dim3(SS / GT, SS / GT, BB * MM), 256, 0, stream>>>(qr, qi, kr, ki, scoresb);
    k_softmax<<<BB * MM * SS, 128, 0, stream>>>(scoresb);
    k_attnav<<<BB * MM * SS, 256, 0, stream>>>(scoresb, vr, vi, gate_mask, score_w, score_b,
                                               conf_w, conf_b, halt_w, halt_b,
                                               prb, pib, scorev, confv, haltv);
    k_stack<<<BB, 256, 0, stream>>>(flat, control, memv, ptrv, st_score_w, st_score_b,
                                    st_conf_w, st_conf_b, readv, stv);
    k_haltp<<<BB, 256, 0, stream>>>(haltv, rem, coeff);
    k_combine<<<BB * SS, 256, 0, stream>>>(prb, pib, scorev, confv, stv, readv, coeff, sr, si, accb);
  }

  k_final<<<(BB * SS * 2 * DD) / 256, 256, 0, stream>>>(accb, rem, sr, si, out);
}

// Round 4
// 4241.991 us; speedup vs baseline: 12.2160x; 2.1782x over previous
//
#include <hip/hip_runtime.h>

#define DD 512
#define MM 4
#define BB 4
#define SS 128
#define KK 32
#define NSTEPS 16
#define EPSF 1e-6f
#define SCALEF 0.04419417382415922f  // 512^-0.5

typedef unsigned short u16;
typedef __bf16 bf16x8 __attribute__((ext_vector_type(8)));
typedef u16 u16x8 __attribute__((ext_vector_type(8)));
typedef float f32x16 __attribute__((ext_vector_type(16)));

__device__ inline void split_bf16(float x, u16& h, u16& l) {
  __bf16 hb = (__bf16)x;
  float hf = (float)hb;
  __bf16 lb = (__bf16)(x - hf);
  h = __builtin_bit_cast(u16, hb);
  l = __builtin_bit_cast(u16, lb);
}

// ---------------- weight fp32 -> split bf16 [row][1024] (hi | lo) ----------------
__global__ void k_convw(const float* __restrict__ src, u16* __restrict__ dst) {
  int idx = blockIdx.x * 256 + threadIdx.x;  // over M*D*D = 1048576
  int row = idx >> 9, k = idx & 511;
  u16 h, l;
  split_bf16(src[idx], h, l);
  dst[(size_t)row * 1024 + k] = h;
  dst[(size_t)row * 1024 + 512 + k] = l;
}

// ---------------- init ----------------
__global__ void k_init(const float* __restrict__ xr, const float* __restrict__ xi,
                       float* __restrict__ sr, float* __restrict__ si,
                       float* __restrict__ acc, float* __restrict__ memv,
                       float* __restrict__ ptrv, float* __restrict__ rem) {
  int idx = blockIdx.x * 256 + threadIdx.x;
  if (idx < BB * SS * 2 * DD) acc[idx] = 0.f;
  if (idx < BB * SS * DD) { sr[idx] = xr[idx]; si[idx] = xi[idx]; }
  if (idx < BB * KK * 2 * DD) memv[idx] = 0.f;
  if (idx < BB * KK) ptrv[idx] = ((idx & (KK - 1)) == 0) ? 1.f : 0.f;
  if (idx < BB) rem[idx] = 1.f;
}

// ---------------- c = 0.5x + 0.5s -> split bf16 ----------------
__global__ void k_prep(const float* __restrict__ xr, const float* __restrict__ xi,
                       const float* __restrict__ sr, const float* __restrict__ si,
                       u16* __restrict__ crbf, u16* __restrict__ cibf) {
  int idx = blockIdx.x * 256 + threadIdx.x;  // < B*S*D
  int row = idx >> 9, d = idx & 511;
  float cr = 0.5f * xr[idx] + 0.5f * sr[idx];
  float ci = 0.5f * xi[idx] + 0.5f * si[idx];
  u16 h, l;
  split_bf16(cr, h, l);
  crbf[(size_t)row * 1024 + d] = h;
  crbf[(size_t)row * 1024 + 512 + d] = l;
  split_bf16(ci, h, l);
  cibf[(size_t)row * 1024 + d] = h;
  cibf[(size_t)row * 1024 + 512 + d] = l;
}

// ---------------- flat_in (mean over S) + control softmax ----------------
__global__ void k_flatctrl(const float* __restrict__ sr, const float* __restrict__ si,
                           const float* __restrict__ ctrl_w, const float* __restrict__ ctrl_b,
                           float* __restrict__ flat_in, float* __restrict__ control) {
  int b = blockIdx.x;
  int tid = threadIdx.x;  // 256
  __shared__ float red[3 * 256];
  float d0 = 0.f, d1 = 0.f, d2 = 0.f;
  for (int i = 0; i < 4; i++) {
    int e = tid + i * 256;  // 0..1023
    const float* basep = (e < DD) ? sr : si;
    int d = (e < DD) ? e : (e - DD);
    float sum = 0.f;
    int base = b * SS * DD + d;
    for (int s = 0; s < SS; s++) sum += basep[base + s * DD];
    float fv = sum * (1.0f / SS);
    flat_in[b * 2 * DD + e] = fv;
    d0 += fv * ctrl_w[e * 3 + 0];
    d1 += fv * ctrl_w[e * 3 + 1];
    d2 += fv * ctrl_w[e * 3 + 2];
  }
  red[tid] = d0; red[256 + tid] = d1; red[512 + tid] = d2;
  __syncthreads();
  for (int off = 128; off > 0; off >>= 1) {
    if (tid < off) {
      red[tid] += red[tid + off];
      red[256 + tid] += red[256 + tid + off];
      red[512 + tid] += red[512 + tid + off];
    }
    __syncthreads();
  }
  if (tid == 0) {
    float l0 = red[0] + ctrl_b[0], l1 = red[256] + ctrl_b[1], l2 = red[512] + ctrl_b[2];
    float mx = fmaxf(l0, fmaxf(l1, l2));
    float e0 = expf(l0 - mx), e1 = expf(l1 - mx), e2 = expf(l2 - mx);
    float s = e0 + e1 + e2;
    control[b * 3 + 0] = e0 / s;
    control[b * 3 + 1] = e1 / s;
    control[b * 3 + 2] = e2 / s;
  }
}

// ---------------- complex NT GEMM via 3-term split-bf16 MFMA ----------------
// x*y ~= xh*yh + xl*yh + xh*yl  (drop xl*yl ~ 2^-18)
// a_bmsd=0: A row = b*S+s (dense).  a_bmsd=1: A row = (b*M+m)*S+s.
// out_mode=0: Cr/Ci are fp32 [BMS][512].  out_mode=1: Cr/Ci are u16 split [BMS][1024].
#define LSTR 72  // LDS row stride in bf16 elems (16B aligned, non-pow2 banks)
__global__ __launch_bounds__(256) void k_gemm_mfma(
    const u16* __restrict__ Ar, const u16* __restrict__ Ai,
    const u16* __restrict__ Wr, const u16* __restrict__ Wi,
    void* __restrict__ Cr, void* __restrict__ Ci, int a_bmsd, int out_mode) {
  __shared__ u16 sAr[64][LSTR], sAi[64][LSTR], sWr[64][LSTR], sWi[64][LSTR];
  int m = blockIdx.z;
  int row_blk = blockIdx.y * 64, o_blk = blockIdx.x * 64;
  int tid = threadIdx.x;

  // staging indices: each thread loads 16B per (array, half)
  int lrow = tid >> 3;           // 0..31
  int lk8 = (tid & 7) << 3;      // 0..56
  int gr0 = row_blk + lrow, gr1 = gr0 + 32;
  size_t arow0, arow1;
  if (a_bmsd) {
    arow0 = (size_t)(((gr0 >> 7) * MM + m) * SS + (gr0 & (SS - 1)));
    arow1 = (size_t)(((gr1 >> 7) * MM + m) * SS + (gr1 & (SS - 1)));
  } else {
    arow0 = (size_t)gr0; arow1 = (size_t)gr1;
  }
  size_t wrow0 = (size_t)m * DD + o_blk + lrow;
  size_t wrow1 = wrow0 + 32;

  // compute indices
  int wave = tid >> 6, lane = tid & 63;
  int wrow = (wave >> 1) * 32, wcol = (wave & 1) * 32;
  int l31 = lane & 31, khalf = (lane >> 5) * 8;

  f32x16 accP, accN, accI;
  for (int i = 0; i < 16; i++) { accP[i] = 0.f; accN[i] = 0.f; accI[i] = 0.f; }

  for (int it = 0; it < 24; ++it) {
    int seg = it >> 3;               // 0,1,2
    int k0 = (it & 7) * 64;          // 0..448
    int aofs = (seg == 1) ? 512 : 0; // A: lo half for seg1
    int wofs = (seg == 2) ? 512 : 0; // W: lo half for seg2
    u16x8 ar0 = *(const u16x8*)&Ar[arow0 * 1024 + aofs + k0 + lk8];
    u16x8 ar1 = *(const u16x8*)&Ar[arow1 * 1024 + aofs + k0 + lk8];
    u16x8 ai0 = *(const u16x8*)&Ai[arow0 * 1024 + aofs + k0 + lk8];
    u16x8 ai1 = *(const u16x8*)&Ai[arow1 * 1024 + aofs + k0 + lk8];
    u16x8 wr0 = *(const u16x8*)&Wr[wrow0 * 1024 + wofs + k0 + lk8];
    u16x8 wr1 = *(const u16x8*)&Wr[wrow1 * 1024 + wofs + k0 + lk8];
    u16x8 wi0 = *(const u16x8*)&Wi[wrow0 * 1024 + wofs + k0 + lk8];
    u16x8 wi1 = *(const u16x8*)&Wi[wrow1 * 1024 + wofs + k0 + lk8];
    __syncthreads();  // previous iter's LDS reads done
    *(u16x8*)&sAr[lrow][lk8] = ar0;
    *(u16x8*)&sAr[lrow + 32][lk8] = ar1;
    *(u16x8*)&sAi[lrow][lk8] = ai0;
    *(u16x8*)&sAi[lrow + 32][lk8] = ai1;
    *(u16x8*)&sWr[lrow][lk8] = wr0;
    *(u16x8*)&sWr[lrow + 32][lk8] = wr1;
    *(u16x8*)&sWi[lrow][lk8] = wi0;
    *(u16x8*)&sWi[lrow + 32][lk8] = wi1;
    __syncthreads();
#pragma unroll
    for (int kk = 0; kk < 64; kk += 16) {
      bf16x8 fAr = *(const bf16x8*)&sAr[wrow + l31][kk + khalf];
      bf16x8 fAi = *(const bf16x8*)&sAi[wrow + l31][kk + khalf];
      bf16x8 fWr = *(const bf16x8*)&sWr[wcol + l31][kk + khalf];
      bf16x8 fWi = *(const bf16x8*)&sWi[wcol + l31][kk + khalf];
      accP = __builtin_amdgcn_mfma_f32_32x32x16_bf16(fAr, fWr, accP, 0, 0, 0);
      accN = __builtin_amdgcn_mfma_f32_32x32x16_bf16(fAi, fWi, accN, 0, 0, 0);
      accI = __builtin_amdgcn_mfma_f32_32x32x16_bf16(fAi, fWr, accI, 0, 0, 0);
      accI = __builtin_amdgcn_mfma_f32_32x32x16_bf16(fAr, fWi, accI, 0, 0, 0);
    }
  }

  int o = o_blk + wcol + l31;
#pragma unroll
  for (int reg = 0; reg < 16; reg++) {
    int r_in = (reg & 3) + 8 * (reg >> 2) + 4 * (lane >> 5);
    int gr = row_blk + wrow + r_in;
    int b = gr >> 7, s = gr & (SS - 1);
    size_t crow = (size_t)((b * MM + m) * SS + s);
    float vR = accP[reg] - accN[reg];
    float vI = accI[reg];
    if (out_mode == 0) {
      ((float*)Cr)[crow * DD + o] = vR;
      ((float*)Ci)[crow * DD + o] = vI;
    } else {
      u16 h, l;
      split_bf16(vR, h, l);
      ((u16*)Cr)[crow * 1024 + o] = h;
      ((u16*)Cr)[crow * 1024 + 512 + o] = l;
      split_bf16(vI, h, l);
      ((u16*)Ci)[crow * 1024 + o] = h;
      ((u16*)Ci)[crow * 1024 + 512 + o] = l;
    }
  }
}

// ---------------- scores = (qr.kr + qi.ki) * SCALE via 3-term split-bf16 MFMA ----------------
// Q, K split-bf16 [bm*S + row][1024].  Output scores fp32 [bm*S+s][S].
__global__ __launch_bounds__(256) void k_scores_mfma(
    const u16* __restrict__ Q_r, const u16* __restrict__ Q_i,
    const u16* __restrict__ K_r, const u16* __restrict__ K_i,
    float* __restrict__ scores) {
  __shared__ u16 sQr[64][LSTR], sQi[64][LSTR], sKr[64][LSTR], sKi[64][LSTR];
  int bm = blockIdx.z;
  int s_blk = blockIdx.y * 64, t_blk = blockIdx.x * 64;
  int tid = threadIdx.x;

  int lrow = tid >> 3;           // 0..31
  int lk8 = (tid & 7) << 3;      // 0..56
  size_t qrow0 = (size_t)(bm * SS + s_blk + lrow), qrow1 = qrow0 + 32;
  size_t krow0 = (size_t)(bm * SS + t_blk + lrow), krow1 = krow0 + 32;

  int wave = tid >> 6, lane = tid & 63;
  int wrow = (wave >> 1) * 32, wcol = (wave & 1) * 32;
  int l31 = lane & 31, khalf = (lane >> 5) * 8;

  f32x16 acc;
  for (int i = 0; i < 16; i++) acc[i] = 0.f;

  for (int it = 0; it < 24; ++it) {
    int seg = it >> 3;
    int k0 = (it & 7) * 64;
    int qofs = (seg == 1) ? 512 : 0;
    int kofs = (seg == 2) ? 512 : 0;
    u16x8 qr0 = *(const u16x8*)&Q_r[qrow0 * 1024 + qofs + k0 + lk8];
    u16x8 qr1 = *(const u16x8*)&Q_r[qrow1 * 1024 + qofs + k0 + lk8];
    u16x8 qi0 = *(const u16x8*)&Q_i[qrow0 * 1024 + qofs + k0 + lk8];
    u16x8 qi1 = *(const u16x8*)&Q_i[qrow1 * 1024 + qofs + k0 + lk8];
    u16x8 kr0 = *(const u16x8*)&K_r[krow0 * 1024 + kofs + k0 + lk8];
    u16x8 kr1 = *(const u16x8*)&K_r[krow1 * 1024 + kofs + k0 + lk8];
    u16x8 ki0 = *(const u16x8*)&K_i[krow0 * 1024 + kofs + k0 + lk8];
    u16x8 ki1 = *(const u16x8*)&K_i[krow1 * 1024 + kofs + k0 + lk8];
    __syncthreads();
    *(u16x8*)&sQr[lrow][lk8] = qr0;
    *(u16x8*)&sQr[lrow + 32][lk8] = qr1;
    *(u16x8*)&sQi[lrow][lk8] = qi0;
    *(u16x8*)&sQi[lrow + 32][lk8] = qi1;
    *(u16x8*)&sKr[lrow][lk8] = kr0;
    *(u16x8*)&sKr[lrow + 32][lk8] = kr1;
    *(u16x8*)&sKi[lrow][lk8] = ki0;
    *(u16x8*)&sKi[lrow + 32][lk8] = ki1;
    __syncthreads();
#pragma unroll
    for (int kk = 0; kk < 64; kk += 16) {
      bf16x8 fQr = *(const bf16x8*)&sQr[wrow + l31][kk + khalf];
      bf16x8 fQi = *(const bf16x8*)&sQi[wrow + l31][kk + khalf];
      bf16x8 fKr = *(const bf16x8*)&sKr[wcol + l31][kk + khalf];
      bf16x8 fKi = *(const bf16x8*)&sKi[wcol + l31][kk + khalf];
      acc = __builtin_amdgcn_mfma_f32_32x32x16_bf16(fQr, fKr, acc, 0, 0, 0);
      acc = __builtin_amdgcn_mfma_f32_32x32x16_bf16(fQi, fKi, acc, 0, 0, 0);
    }
  }

  int t = t_blk + wcol + l31;
#pragma unroll
  for (int reg = 0; reg < 16; reg++) {
    int r_in = (reg & 3) + 8 * (reg >> 2) + 4 * (lane >> 5);
    int s = s_blk + wrow + r_in;
    scores[((size_t)bm * SS + s) * SS + t] = acc[reg] * SCALEF;
  }
}

// ---------------- magnitude LN + phase renorm + mod scale -> split bf16 ----------------
__global__ void k_lnphase(const float* __restrict__ zr, const float* __restrict__ zi,
                          const float* __restrict__ ln_scale, const float* __restrict__ ln_shift,
                          const float* __restrict__ mod_bias,
                          u16* __restrict__ zbr, u16* __restrict__ zbi) {
  int row = blockIdx.x;            // (b*M+m)*S + s
  int m = (row >> 7) & (MM - 1);
  int tid = threadIdx.x;           // 128
  size_t base = (size_t)row * DD;
  float zrv[4], ziv[4], rv[4];
  float sum = 0.f, sumsq = 0.f;
#pragma unroll
  for (int i = 0; i < 4; i++) {
    int o = tid + i * 128;
    float a = zr[base + o], bv = zi[base + o];
    zrv[i] = a; ziv[i] = bv;
    float r = sqrtf(a * a + bv * bv);
    rv[i] = r;
    float mg = r + EPSF;
    sum += mg;
    sumsq += mg * mg;
  }
  __shared__ float rs[128], rq[128];
  rs[tid] = sum; rq[tid] = sumsq;
  __syncthreads();
  for (int off = 64; off > 0; off >>= 1) {
    if (tid < off) { rs[tid] += rs[tid + off]; rq[tid] += rq[tid + off]; }
    __syncthreads();
  }
  float mean = rs[0] * (1.0f / DD);
  float var = (rq[0] - (float)DD * mean * mean) * (1.0f / (DD - 1));
  float inv = 1.0f / sqrtf(var + EPSF);
#pragma unroll
  for (int i = 0; i < 4; i++) {
    int o = tid + i * 128;
    float mg = rv[i] + EPSF;
    float nm = (mg - mean) * inv * ln_scale[m * DD + o] + ln_shift[m * DD + o];
    float r = rv[i];
    float cosp, sinp;
    if (r > 0.f) { cosp = zrv[i] / r; sinp = ziv[i] / r; }
    else { cosp = 1.f; sinp = 0.f; }
    float z1r = nm * cosp, z1i = nm * sinp;
    float nrm = sqrtf(z1r * z1r + z1i * z1i) + EPSF;
    float sc = fmaxf(nrm + mod_bias[m * DD + o], 0.f) / nrm;
    u16 h, l;
    split_bf16(z1r * sc, h, l);
    zbr[(size_t)row * 1024 + o] = h;
    zbr[(size_t)row * 1024 + 512 + o] = l;
    split_bf16(z1i * sc, h, l);
    zbi[(size_t)row * 1024 + o] = h;
    zbi[(size_t)row * 1024 + 512 + o] = l;
  }
}

// ---------------- row softmax over t (in place) ----------------
__global__ void k_softmax(float* __restrict__ scores) {
  int row = blockIdx.x;
  int tid = threadIdx.x;  // 128
  __shared__ float buf[128];
  size_t base = (size_t)row * SS;
  float v = scores[base + tid];
  buf[tid] = v;
  __syncthreads();
  for (int off = 64; off > 0; off >>= 1) {
    if (tid < off) buf[tid] = fmaxf(buf[tid], buf[tid + off]);
    __syncthreads();
  }
  float mx = buf[0];
  __syncthreads();
  float e = expf(v - mx);
  buf[tid] = e;
  __syncthreads();
  for (int off = 64; off > 0; off >>= 1) {
    if (tid < off) buf[tid] += buf[tid + off];
    __syncthreads();
  }
  float s = buf[0];
  scores[base + tid] = e / s;
}

// ---------------- AV + gate + score/conf/halt heads ----------------
__global__ void k_attnav(const float* __restrict__ attn, const float* __restrict__ vr,
                         const float* __restrict__ vi, const float* __restrict__ gate_mask,
                         const float* __restrict__ score_w, const float* __restrict__ score_b,
                         const float* __restrict__ conf_w, const float* __restrict__ conf_b,
                         const float* __restrict__ halt_w, const float* __restrict__ halt_b,
                         float* __restrict__ pr, float* __restrict__ pi,
                         float* __restrict__ score, float* __restrict__ conf,
                         float* __restrict__ halt) {
  int row = blockIdx.x;           // (b*M+m)*S + s
  int bm = row >> 7;
  int m = bm & (MM - 1);
  int tid = threadIdx.x;          // 256
  __shared__ float att[SS];
  __shared__ float r0[256], r1[256], r2[256];
  if (tid < SS) att[tid] = attn[(size_t)row * SS + tid];
  __syncthreads();
  size_t vbase = (size_t)bm * SS * DD;
  float sp = 0.f, cp = 0.f, hp = 0.f;
#pragma unroll
  for (int i = 0; i < 2; i++) {
    int d = tid + i * 256;
    float aR = 0.f, aI = 0.f;
    for (int t = 0; t < SS; t++) {
      float a = att[t];
      aR += a * vr[vbase + (size_t)t * DD + d];
      aI += a * vi[vbase + (size_t)t * DD + d];
    }
    float g = 1.f / (1.f + expf(-gate_mask[m * DD + d]));
    float pR = aR * g, pI = aI * g;
    pr[(size_t)row * DD + d] = pR;
    pi[(size_t)row * DD + d] = pI;
    sp += pR * score_w[m * 2 * DD + d] + pI * score_w[m * 2 * DD + DD + d];
    cp += pR * conf_w[m * 2 * DD + d] + pI * conf_w[m * 2 * DD + DD + d];
    hp += pR * halt_w[m * 2 * DD + d] + pI * halt_w[m * 2 * DD + DD + d];
  }
  r0[tid] = sp; r1[tid] = cp; r2[tid] = hp;
  __syncthreads();
  for (int off = 128; off > 0; off >>= 1) {
    if (tid < off) { r0[tid] += r0[tid + off]; r1[tid] += r1[tid + off]; r2[tid] += r2[tid + off]; }
    __syncthreads();
  }
  if (tid == 0) {
    score[row] = r0[0] + score_b[m];
    conf[row] = 1.f / (1.f + expf(-(r1[0] + conf_b[m])));
    halt[row] = r2[0] + halt_b[m];
  }
}

// ---------------- stack update (per b) ----------------
__global__ void k_stack(const float* __restrict__ flat_in, const float* __restrict__ control,
                        float* __restrict__ memv, float* __restrict__ ptrv,
                        const float* __restrict__ st_score_w, const float* __restrict__ st_score_b,
                        const float* __restrict__ st_conf_w, const float* __restrict__ st_conf_b,
                        float* __restrict__ readv, float* __restrict__ stv) {
  int b = blockIdx.x;
  int tid = threadIdx.x;  // 256
  __shared__ float nptr[KK], wm[KK], ctrl[3];
  __shared__ float red[256], red2[256];
  if (tid < 3) ctrl[tid] = control[b * 3 + tid];
  __syncthreads();
  if (tid < KK) {
    int k = tid;
    float up = ptrv[b * KK + ((k + KK - 1) & (KK - 1))];
    float dn = ptrv[b * KK + ((k + 1) & (KK - 1))];
    float cu = ptrv[b * KK + k];
    nptr[k] = ctrl[0] * up + ctrl[1] * dn + ctrl[2] * cu;
    wm[k] = ctrl[0] * up;
  }
  __syncthreads();
  if (tid == 0) {
    float s = 0.f;
    for (int k = 0; k < KK; k++) s += nptr[k];
    float f = 1.f / (s + EPSF);
    for (int k = 0; k < KK; k++) nptr[k] *= f;
  }
  __syncthreads();
  if (tid < KK) ptrv[b * KK + tid] = nptr[tid];
  float ds = 0.f, dc = 0.f;
#pragma unroll
  for (int i = 0; i < 4; i++) {
    int e = tid + i * 256;
    float fl = flat_in[b * 2 * DD + e];
    float racc = 0.f;
    for (int k = 0; k < KK; k++) {
      size_t idx = ((size_t)(b * KK + k)) * 2 * DD + e;
      float nm = wm[k] * fl + memv[idx] * (1.f - wm[k]);
      memv[idx] = nm;
      racc += nm * nptr[k];
    }
    readv[b * 2 * DD + e] = racc;
    ds += racc * st_score_w[e];
    dc += racc * st_conf_w[e];
  }
  red[tid] = ds; red2[tid] = dc;
  __syncthreads();
  for (int off = 128; off > 0; off >>= 1) {
    if (tid < off) { red[tid] += red[tid + off]; red2[tid] += red2[tid + off]; }
    __syncthreads();
  }
  if (tid == 0) {
    stv[b] = red[0] + st_score_b[0];
    stv[BB + b] = 1.f / (1.f + expf(-(red2[0] + st_conf_b[0])));
  }
}

// ---------------- p = mean sigmoid(halt); coeff = p*rem; rem *= 1-p ----------------
__global__ void k_haltp(const float* __restrict__ halt, float* __restrict__ rem,
                        float* __restrict__ coeff) {
  int b = blockIdx.x;
  int tid = threadIdx.x;  // 256
  __shared__ float red[256];
  float v0 = halt[b * MM * SS + tid];
  float v1 = halt[b * MM * SS + 256 + tid];
  red[tid] = 1.f / (1.f + expf(-v0)) + 1.f / (1.f + expf(-v1));
  __syncthreads();
  for (int off = 128; off > 0; off >>= 1) {
    if (tid < off) red[tid] += red[tid + off];
    __syncthreads();
  }
  if (tid == 0) {
    float p = red[0] * (1.0f / (MM * SS));
    float r = rem[b];
    coeff[b] = p * r;
    rem[b] = r * (1.f - p);
  }
}

// ---------------- module-mix softmax + new state + acc update ----------------
__global__ void k_combine(const float* __restrict__ pr, const float* __restrict__ pi,
                          const float* __restrict__ score, const float* __restrict__ conf,
                          const float* __restrict__ stv, const float* __restrict__ readv,
                          const float* __restrict__ coeff,
                          float* __restrict__ sr, float* __restrict__ si, float* __restrict__ acc) {
  int bs = blockIdx.x;             // b*S + s
  int b = bs >> 7, s = bs & (SS - 1);
  int tid = threadIdx.x;           // 256
  __shared__ float w[5];
  if (tid == 0) {
    float l[5];
    for (int m = 0; m < MM; m++) {
      int r = (b * MM + m) * SS + s;
      l[m] = score[r] * conf[r];
    }
    l[4] = stv[b] * stv[BB + b];
    float mx = l[0];
    for (int j = 1; j < 5; j++) mx = fmaxf(mx, l[j]);
    float sum = 0.f;
    for (int j = 0; j < 5; j++) { l[j] = expf(l[j] - mx); sum += l[j]; }
    for (int j = 0; j < 5; j++) w[j] = l[j] / sum;
  }
  __syncthreads();
  float cf = coeff[b];
#pragma unroll
  for (int i = 0; i < 2; i++) {
    int d = tid + i * 256;
    float nsr = w[4] * readv[b * 2 * DD + d];
    float nsi = w[4] * readv[b * 2 * DD + DD + d];
#pragma unroll
    for (int m = 0; m < MM; m++) {
      size_t off = ((size_t)((b * MM + m) * SS + s)) * DD + d;
      nsr += w[m] * pr[off];
      nsi += w[m] * pi[off];
    }
    sr[(size_t)bs * DD + d] = nsr;
    si[(size_t)bs * DD + d] = nsi;
    size_t aoff = (size_t)bs * 2 * DD;
    acc[aoff + d] += cf * nsr;
    acc[aoff + DD + d] += cf * nsi;
  }
}

// ---------------- out = acc + rem * concat(sr, si) ----------------
__global__ void k_final(const float* __restrict__ acc, const float* __restrict__ rem,
                        const float* __restrict__ sr, const float* __restrict__ si,
                        float* __restrict__ out) {
  int idx = blockIdx.x * 256 + threadIdx.x;  // < B*S*2D
  int e = idx & (2 * DD - 1);
  int bs = idx >> 10;
  int b = bs >> 7;
  float v = (e < DD) ? sr[(size_t)bs * DD + e] : si[(size_t)bs * DD + e - DD];
  out[idx] = acc[idx] + rem[b] * v;
}

extern "C" void kernel_launch(void* const* d_in, const int* in_sizes, int n_in,
                              void* d_out, int out_size, void* d_ws, size_t ws_size,
                              hipStream_t stream) {
  const float* xr = (const float*)d_in[0];
  const float* xi = (const float*)d_in[1];
  const float* Wl_r = (const float*)d_in[2];
  const float* Wl_i = (const float*)d_in[3];
  const float* Wq_r = (const float*)d_in[4];
  const float* Wq_i = (const float*)d_in[5];
  const float* Wk_r = (const float*)d_in[6];
  const float* Wk_i = (const float*)d_in[7];
  const float* Wv_r = (const float*)d_in[8];
  const float* Wv_i = (const float*)d_in[9];
  const float* ln_scale = (const float*)d_in[10];
  const float* ln_shift = (const float*)d_in[11];
  const float* mod_bias = (const float*)d_in[12];
  const float* gate_mask = (const float*)d_in[13];
  const float* score_w = (const float*)d_in[14];
  const float* score_b = (const float*)d_in[15];
  const float* conf_w = (const float*)d_in[16];
  const float* conf_b = (const float*)d_in[17];
  const float* halt_w = (const float*)d_in[18];
  const float* halt_b = (const float*)d_in[19];
  const float* ctrl_w = (const float*)d_in[20];
  const float* ctrl_b = (const float*)d_in[21];
  const float* st_score_w = (const float*)d_in[22];
  const float* st_score_b = (const float*)d_in[23];
  const float* st_conf_w = (const float*)d_in[24];
  const float* st_conf_b = (const float*)d_in[25];
  float* out = (float*)d_out;

  const int BSD = BB * SS * DD;        // 262144
  const int BMSD = BB * MM * SS * DD;  // 1048576
  const size_t WSLOT = (size_t)MM * DD * 1024;  // 2097152 u16 per weight matrix

  char* pc = (char*)d_ws;
  float* sr = (float*)pc; pc += (size_t)BSD * 4;
  float* si = (float*)pc; pc += (size_t)BSD * 4;
  float* zr = (float*)pc; pc += (size_t)BMSD * 4;
  float* zi = (float*)pc; pc += (size_t)BMSD * 4;
  float* vr = (float*)pc; pc += (size_t)BMSD * 4;
  float* vi = (float*)pc; pc += (size_t)BMSD * 4;
  float* prb = (float*)pc; pc += (size_t)BMSD * 4;
  float* pib = (float*)pc; pc += (size_t)BMSD * 4;
  float* scoresb = (float*)pc; pc += (size_t)BB * MM * SS * SS * 4;
  float* scorev = (float*)pc; pc += (size_t)BB * MM * SS * 4;
  float* confv = (float*)pc; pc += (size_t)BB * MM * SS * 4;
  float* haltv = (float*)pc; pc += (size_t)BB * MM * SS * 4;
  float* flat = (float*)pc; pc += (size_t)BB * 2 * DD * 4;
  float* control = (float*)pc; pc += 64;
  float* memv = (float*)pc; pc += (size_t)BB * KK * 2 * DD * 4;
  float* ptrv = (float*)pc; pc += (size_t)BB * KK * 4;
  float* readv = (float*)pc; pc += (size_t)BB * 2 * DD * 4;
  float* stv = (float*)pc; pc += (size_t)2 * BB * 4;
  float* accb = (float*)pc; pc += (size_t)BB * SS * 2 * DD * 4;
  float* rem = (float*)pc; pc += (size_t)BB * 4;
  float* coeff = (float*)pc; pc += (size_t)BB * 4;
  u16* crbf = (u16*)pc; pc += (size_t)BB * SS * 1024 * 2;
  u16* cibf = (u16*)pc; pc += (size_t)BB * SS * 1024 * 2;
  u16* zbr = (u16*)pc; pc += (size_t)BB * MM * SS * 1024 * 2;
  u16* zbi = (u16*)pc; pc += (size_t)BB * MM * SS * 1024 * 2;
  u16* qbr = (u16*)pc; pc += (size_t)BB * MM * SS * 1024 * 2;
  u16* qbi = (u16*)pc; pc += (size_t)BB * MM * SS * 1024 * 2;
  u16* kbr = (u16*)pc; pc += (size_t)BB * MM * SS * 1024 * 2;
  u16* kbi = (u16*)pc; pc += (size_t)BB * MM * SS * 1024 * 2;
  u16* wbf = (u16*)pc; pc += 8 * WSLOT * 2;  // Wl_r,Wl_i,Wq_r,Wq_i,Wk_r,Wk_i,Wv_r,Wv_i

  // one-time (per launch) weight conversion: 8 matrices of 1M elems
  k_convw<<<4096, 256, 0, stream>>>(Wl_r, wbf + 0 * WSLOT);
  k_convw<<<4096, 256, 0, stream>>>(Wl_i, wbf + 1 * WSLOT);
  k_convw<<<4096, 256, 0, stream>>>(Wq_r, wbf + 2 * WSLOT);
  k_convw<<<4096, 256, 0, stream>>>(Wq_i, wbf + 3 * WSLOT);
  k_convw<<<4096, 256, 0, stream>>>(Wk_r, wbf + 4 * WSLOT);
  k_convw<<<4096, 256, 0, stream>>>(Wk_i, wbf + 5 * WSLOT);
  k_convw<<<4096, 256, 0, stream>>>(Wv_r, wbf + 6 * WSLOT);
  k_convw<<<4096, 256, 0, stream>>>(Wv_i, wbf + 7 * WSLOT);

  k_init<<<2048, 256, 0, stream>>>(xr, xi, sr, si, accb, memv, ptrv, rem);

  dim3 ggrid(DD / 64, (BB * SS) / 64, MM);   // (8, 8, 4)
  dim3 sgrid(SS / 64, SS / 64, BB * MM);     // (2, 2, 16)

  for (int step = 0; step < NSTEPS; ++step) {
    k_prep<<<BSD / 256, 256, 0, stream>>>(xr, xi, sr, si, crbf, cibf);
    k_flatctrl<<<BB, 256, 0, stream>>>(sr, si, ctrl_w, ctrl_b, flat, control);
    k_gemm_mfma<<<ggrid, 256, 0, stream>>>(crbf, cibf, wbf + 0 * WSLOT, wbf + 1 * WSLOT, zr, zi, 0, 0);
    k_lnphase<<<BB * MM * SS, 128, 0, stream>>>(zr, zi, ln_scale, ln_shift, mod_bias, zbr, zbi);
    k_gemm_mfma<<<ggrid, 256, 0, stream>>>(zbr, zbi, wbf + 2 * WSLOT, wbf + 3 * WSLOT, qbr, qbi, 1, 1);
    k_gemm_mfma<<<ggrid, 256, 0, stream>>>(zbr, zbi, wbf + 4 * WSLOT, wbf + 5 * WSLOT, kbr, kbi, 1, 1);
    k_gemm_mfma<<<ggrid, 256, 0, stream>>>(zbr, zbi, wbf + 6 * WSLOT, wbf + 7 * WSLOT, vr, vi, 1, 0);
    k_scores_mfma<<<sgrid, 256, 0, stream>>>(qbr, qbi, kbr, kbi, scoresb);
    k_softmax<<<BB * MM * SS, 128, 0, stream>>>(scoresb);
    k_attnav<<<BB * MM * SS, 256, 0, stream>>>(scoresb, vr, vi, gate_mask, score_w, score_b,
                                               conf_w, conf_b, halt_w, halt_b,
                                               prb, pib, scorev, confv, haltv);
    k_stack<<<BB, 256, 0, stream>>>(flat, control, memv, ptrv, st_score_w, st_score_b,
                                    st_conf_w, st_conf_b, readv, stv);
    k_haltp<<<BB, 256, 0, stream>>>(haltv, rem, coeff);
    k_combine<<<BB * SS, 256, 0, stream>>>(prb, pib, scorev, confv, stv, readv, coeff, sr, si, accb);
  }

  k_final<<<(BB * SS * 2 * DD) / 256, 256, 0, stream>>>(accb, rem, sr, si, out);
}

// Round 5
// 2920.702 us; speedup vs baseline: 17.7424x; 1.4524x over previous
//
#include <hip/hip_runtime.h>

#define DD 512
#define MM 4
#define BB 4
#define SS 128
#define KK 32
#define NSTEPS 16
#define EPSF 1e-6f
#define SCALEF 0.04419417382415922f  // 512^-0.5

typedef unsigned short u16;
typedef __bf16 bf16x8 __attribute__((ext_vector_type(8)));
typedef u16 u16x8 __attribute__((ext_vector_type(8)));
typedef float f32x16 __attribute__((ext_vector_type(16)));

__device__ inline void split_bf16(float x, u16& h, u16& l) {
  __bf16 hb = (__bf16)x;
  float hf = (float)hb;
  __bf16 lb = (__bf16)(x - hf);
  h = __builtin_bit_cast(u16, hb);
  l = __builtin_bit_cast(u16, lb);
}

// ---------------- weight fp32 -> split bf16 [row][1024] (hi | lo) ----------------
__global__ void k_convw(const float* __restrict__ src, u16* __restrict__ dst) {
  int idx = blockIdx.x * 256 + threadIdx.x;  // over M*D*D = 1048576
  int row = idx >> 9, k = idx & 511;
  u16 h, l;
  split_bf16(src[idx], h, l);
  dst[(size_t)row * 1024 + k] = h;
  dst[(size_t)row * 1024 + 512 + k] = l;
}

// ---------------- init: state, acc, mem, ptr, rem, and step-0 c = x ----------------
__global__ void k_init(const float* __restrict__ xr, const float* __restrict__ xi,
                       float* __restrict__ sr, float* __restrict__ si,
                       float* __restrict__ acc, float* __restrict__ memv,
                       float* __restrict__ ptrv, float* __restrict__ rem,
                       u16* __restrict__ crbf, u16* __restrict__ cibf) {
  int idx = blockIdx.x * 256 + threadIdx.x;
  if (idx < BB * SS * 2 * DD) acc[idx] = 0.f;
  if (idx < BB * SS * DD) {
    float a = xr[idx], b = xi[idx];
    sr[idx] = a; si[idx] = b;
    int row = idx >> 9, d = idx & 511;
    u16 h, l;
    split_bf16(a, h, l);   // c0 = 0.5x + 0.5x = x
    crbf[(size_t)row * 1024 + d] = h;
    crbf[(size_t)row * 1024 + 512 + d] = l;
    split_bf16(b, h, l);
    cibf[(size_t)row * 1024 + d] = h;
    cibf[(size_t)row * 1024 + 512 + d] = l;
  }
  if (idx < BB * KK * 2 * DD) memv[idx] = 0.f;
  if (idx < BB * KK) ptrv[idx] = ((idx & (KK - 1)) == 0) ? 1.f : 0.f;
  if (idx < BB) rem[idx] = 1.f;
}

// ---------------- flat_in (mean over S, float4) + control softmax + ptr update ----------------
__global__ void k_flatctrl(const float* __restrict__ sr, const float* __restrict__ si,
                           const float* __restrict__ ctrl_w, const float* __restrict__ ctrl_b,
                           float* __restrict__ ptrv, float* __restrict__ flat_in,
                           float* __restrict__ nptrg, float* __restrict__ wmg,
                           float* __restrict__ stacc) {
  int b = blockIdx.x;
  int tid = threadIdx.x;  // 256
  __shared__ float red[3 * 256];
  __shared__ float ctrl[3], optr[KK], nptr_s[KK], wm_s[KK], normf;

  if (tid < KK) optr[tid] = ptrv[b * KK + tid];

  int e4 = tid * 4;  // 0..1020, never straddles the 512 boundary
  const float* basep = (e4 < DD) ? sr : si;
  int d4 = (e4 < DD) ? e4 : (e4 - DD);
  float4 accv = make_float4(0.f, 0.f, 0.f, 0.f);
  size_t base = (size_t)b * SS * DD + d4;
  for (int s = 0; s < SS; s++) {
    float4 v = *(const float4*)&basep[base + (size_t)s * DD];
    accv.x += v.x; accv.y += v.y; accv.z += v.z; accv.w += v.w;
  }
  accv.x *= (1.0f / SS); accv.y *= (1.0f / SS); accv.z *= (1.0f / SS); accv.w *= (1.0f / SS);
  *(float4*)&flat_in[b * 2 * DD + e4] = accv;
  float fv[4] = {accv.x, accv.y, accv.z, accv.w};
  float d0 = 0.f, d1 = 0.f, d2 = 0.f;
#pragma unroll
  for (int j = 0; j < 4; j++) {
    d0 += fv[j] * ctrl_w[(e4 + j) * 3 + 0];
    d1 += fv[j] * ctrl_w[(e4 + j) * 3 + 1];
    d2 += fv[j] * ctrl_w[(e4 + j) * 3 + 2];
  }
  red[tid] = d0; red[256 + tid] = d1; red[512 + tid] = d2;
  __syncthreads();
  for (int off = 128; off > 0; off >>= 1) {
    if (tid < off) {
      red[tid] += red[tid + off];
      red[256 + tid] += red[256 + tid + off];
      red[512 + tid] += red[512 + tid + off];
    }
    __syncthreads();
  }
  if (tid == 0) {
    float l0 = red[0] + ctrl_b[0], l1 = red[256] + ctrl_b[1], l2 = red[512] + ctrl_b[2];
    float mx = fmaxf(l0, fmaxf(l1, l2));
    float e0 = expf(l0 - mx), e1 = expf(l1 - mx), e2 = expf(l2 - mx);
    float s = e0 + e1 + e2;
    ctrl[0] = e0 / s; ctrl[1] = e1 / s; ctrl[2] = e2 / s;
    stacc[b * 2] = 0.f; stacc[b * 2 + 1] = 0.f;
  }
  __syncthreads();
  if (tid < KK) {
    float up = optr[(tid + KK - 1) & (KK - 1)];
    float dn = optr[(tid + 1) & (KK - 1)];
    float cu = optr[tid];
    nptr_s[tid] = ctrl[0] * up + ctrl[1] * dn + ctrl[2] * cu;
    wm_s[tid] = ctrl[0] * up;
  }
  __syncthreads();
  if (tid == 0) {
    float s = 0.f;
    for (int k = 0; k < KK; k++) s += nptr_s[k];
    normf = 1.f / (s + EPSF);
  }
  __syncthreads();
  if (tid < KK) {
    float np = nptr_s[tid] * normf;
    ptrv[b * KK + tid] = np;
    nptrg[b * KK + tid] = np;
    wmg[b * KK + tid] = wm_s[tid];
  }
}

// ---------------- complex NT GEMM via 3-term split-bf16 MFMA (Wl; fp32 out) ----------------
#define LSTR 72  // LDS row stride in bf16 elems (16B aligned, non-pow2 banks)
__global__ __launch_bounds__(256) void k_gemm_mfma(
    const u16* __restrict__ Ar, const u16* __restrict__ Ai,
    const u16* __restrict__ Wr, const u16* __restrict__ Wi,
    float* __restrict__ Cr, float* __restrict__ Ci) {
  __shared__ u16 sAr[64][LSTR], sAi[64][LSTR], sWr[64][LSTR], sWi[64][LSTR];
  int m = blockIdx.z;
  int row_blk = blockIdx.y * 64, o_blk = blockIdx.x * 64;
  int tid = threadIdx.x;

  int lrow = tid >> 3;           // 0..31
  int lk8 = (tid & 7) << 3;      // 0..56
  int gr0 = row_blk + lrow, gr1 = gr0 + 32;
  size_t arow0 = (size_t)gr0, arow1 = (size_t)gr1;  // a dense (b*S+s)
  size_t wrow0 = (size_t)m * DD + o_blk + lrow;
  size_t wrow1 = wrow0 + 32;

  int wave = tid >> 6, lane = tid & 63;
  int wrow = (wave >> 1) * 32, wcol = (wave & 1) * 32;
  int l31 = lane & 31, khalf = (lane >> 5) * 8;

  f32x16 accP, accN, accI;
  for (int i = 0; i < 16; i++) { accP[i] = 0.f; accN[i] = 0.f; accI[i] = 0.f; }

  for (int it = 0; it < 24; ++it) {
    int seg = it >> 3;
    int k0 = (it & 7) * 64;
    int aofs = (seg == 1) ? 512 : 0;
    int wofs = (seg == 2) ? 512 : 0;
    u16x8 ar0 = *(const u16x8*)&Ar[arow0 * 1024 + aofs + k0 + lk8];
    u16x8 ar1 = *(const u16x8*)&Ar[arow1 * 1024 + aofs + k0 + lk8];
    u16x8 ai0 = *(const u16x8*)&Ai[arow0 * 1024 + aofs + k0 + lk8];
    u16x8 ai1 = *(const u16x8*)&Ai[arow1 * 1024 + aofs + k0 + lk8];
    u16x8 wr0 = *(const u16x8*)&Wr[wrow0 * 1024 + wofs + k0 + lk8];
    u16x8 wr1 = *(const u16x8*)&Wr[wrow1 * 1024 + wofs + k0 + lk8];
    u16x8 wi0 = *(const u16x8*)&Wi[wrow0 * 1024 + wofs + k0 + lk8];
    u16x8 wi1 = *(const u16x8*)&Wi[wrow1 * 1024 + wofs + k0 + lk8];
    __syncthreads();
    *(u16x8*)&sAr[lrow][lk8] = ar0;
    *(u16x8*)&sAr[lrow + 32][lk8] = ar1;
    *(u16x8*)&sAi[lrow][lk8] = ai0;
    *(u16x8*)&sAi[lrow + 32][lk8] = ai1;
    *(u16x8*)&sWr[lrow][lk8] = wr0;
    *(u16x8*)&sWr[lrow + 32][lk8] = wr1;
    *(u16x8*)&sWi[lrow][lk8] = wi0;
    *(u16x8*)&sWi[lrow + 32][lk8] = wi1;
    __syncthreads();
#pragma unroll
    for (int kk = 0; kk < 64; kk += 16) {
      bf16x8 fAr = *(const bf16x8*)&sAr[wrow + l31][kk + khalf];
      bf16x8 fAi = *(const bf16x8*)&sAi[wrow + l31][kk + khalf];
      bf16x8 fWr = *(const bf16x8*)&sWr[wcol + l31][kk + khalf];
      bf16x8 fWi = *(const bf16x8*)&sWi[wcol + l31][kk + khalf];
      accP = __builtin_amdgcn_mfma_f32_32x32x16_bf16(fAr, fWr, accP, 0, 0, 0);
      accN = __builtin_amdgcn_mfma_f32_32x32x16_bf16(fAi, fWi, accN, 0, 0, 0);
      accI = __builtin_amdgcn_mfma_f32_32x32x16_bf16(fAi, fWr, accI, 0, 0, 0);
      accI = __builtin_amdgcn_mfma_f32_32x32x16_bf16(fAr, fWi, accI, 0, 0, 0);
    }
  }

  int o = o_blk + wcol + l31;
#pragma unroll
  for (int reg = 0; reg < 16; reg++) {
    int r_in = (reg & 3) + 8 * (reg >> 2) + 4 * (lane >> 5);
    int gr = row_blk + wrow + r_in;
    int b = gr >> 7, s = gr & (SS - 1);
    size_t crow = (size_t)((b * MM + m) * SS + s);
    Cr[crow * DD + o] = accP[reg] - accN[reg];
    Ci[crow * DD + o] = accI[reg];
  }
}

// ---------------- merged Q/K/V complex NT GEMM: z = m*3 + {0:Q,1:K,2:V} ----------------
__global__ __launch_bounds__(256) void k_gemm_qkv(
    const u16* __restrict__ Ar, const u16* __restrict__ Ai,
    const u16* __restrict__ wbf, size_t WSLOT,
    u16* __restrict__ qbr, u16* __restrict__ qbi,
    u16* __restrict__ kbr, u16* __restrict__ kbi,
    float* __restrict__ vr, float* __restrict__ vi) {
  __shared__ u16 sAr[64][LSTR], sAi[64][LSTR], sWr[64][LSTR], sWi[64][LSTR];
  int zid = blockIdx.z;
  int m = zid / 3, w = zid - 3 * m;
  const u16* Wr = wbf + (size_t)(2 + 2 * w) * WSLOT;
  const u16* Wi = Wr + WSLOT;
  int row_blk = blockIdx.y * 64, o_blk = blockIdx.x * 64;
  int tid = threadIdx.x;

  int lrow = tid >> 3;
  int lk8 = (tid & 7) << 3;
  int gr0 = row_blk + lrow, gr1 = gr0 + 32;
  size_t arow0 = (size_t)(((gr0 >> 7) * MM + m) * SS + (gr0 & (SS - 1)));
  size_t arow1 = (size_t)(((gr1 >> 7) * MM + m) * SS + (gr1 & (SS - 1)));
  size_t wrow0 = (size_t)m * DD + o_blk + lrow;
  size_t wrow1 = wrow0 + 32;

  int wave = tid >> 6, lane = tid & 63;
  int wrow = (wave >> 1) * 32, wcol = (wave & 1) * 32;
  int l31 = lane & 31, khalf = (lane >> 5) * 8;

  f32x16 accP, accN, accI;
  for (int i = 0; i < 16; i++) { accP[i] = 0.f; accN[i] = 0.f; accI[i] = 0.f; }

  for (int it = 0; it < 24; ++it) {
    int seg = it >> 3;
    int k0 = (it & 7) * 64;
    int aofs = (seg == 1) ? 512 : 0;
    int wofs = (seg == 2) ? 512 : 0;
    u16x8 ar0 = *(const u16x8*)&Ar[arow0 * 1024 + aofs + k0 + lk8];
    u16x8 ar1 = *(const u16x8*)&Ar[arow1 * 1024 + aofs + k0 + lk8];
    u16x8 ai0 = *(const u16x8*)&Ai[arow0 * 1024 + aofs + k0 + lk8];
    u16x8 ai1 = *(const u16x8*)&Ai[arow1 * 1024 + aofs + k0 + lk8];
    u16x8 wr0 = *(const u16x8*)&Wr[wrow0 * 1024 + wofs + k0 + lk8];
    u16x8 wr1 = *(const u16x8*)&Wr[wrow1 * 1024 + wofs + k0 + lk8];
    u16x8 wi0 = *(const u16x8*)&Wi[wrow0 * 1024 + wofs + k0 + lk8];
    u16x8 wi1 = *(const u16x8*)&Wi[wrow1 * 1024 + wofs + k0 + lk8];
    __syncthreads();
    *(u16x8*)&sAr[lrow][lk8] = ar0;
    *(u16x8*)&sAr[lrow + 32][lk8] = ar1;
    *(u16x8*)&sAi[lrow][lk8] = ai0;
    *(u16x8*)&sAi[lrow + 32][lk8] = ai1;
    *(u16x8*)&sWr[lrow][lk8] = wr0;
    *(u16x8*)&sWr[lrow + 32][lk8] = wr1;
    *(u16x8*)&sWi[lrow][lk8] = wi0;
    *(u16x8*)&sWi[lrow + 32][lk8] = wi1;
    __syncthreads();
#pragma unroll
    for (int kk = 0; kk < 64; kk += 16) {
      bf16x8 fAr = *(const bf16x8*)&sAr[wrow + l31][kk + khalf];
      bf16x8 fAi = *(const bf16x8*)&sAi[wrow + l31][kk + khalf];
      bf16x8 fWr = *(const bf16x8*)&sWr[wcol + l31][kk + khalf];
      bf16x8 fWi = *(const bf16x8*)&sWi[wcol + l31][kk + khalf];
      accP = __builtin_amdgcn_mfma_f32_32x32x16_bf16(fAr, fWr, accP, 0, 0, 0);
      accN = __builtin_amdgcn_mfma_f32_32x32x16_bf16(fAi, fWi, accN, 0, 0, 0);
      accI = __builtin_amdgcn_mfma_f32_32x32x16_bf16(fAi, fWr, accI, 0, 0, 0);
      accI = __builtin_amdgcn_mfma_f32_32x32x16_bf16(fAr, fWi, accI, 0, 0, 0);
    }
  }

  int o = o_blk + wcol + l31;
#pragma unroll
  for (int reg = 0; reg < 16; reg++) {
    int r_in = (reg & 3) + 8 * (reg >> 2) + 4 * (lane >> 5);
    int gr = row_blk + wrow + r_in;
    int b = gr >> 7, s = gr & (SS - 1);
    size_t crow = (size_t)((b * MM + m) * SS + s);
    float vR = accP[reg] - accN[reg];
    float vI = accI[reg];
    if (w == 2) {
      vr[crow * DD + o] = vR;
      vi[crow * DD + o] = vI;
    } else {
      u16* Cr = (w == 0) ? qbr : kbr;
      u16* Ci = (w == 0) ? qbi : kbi;
      u16 h, l;
      split_bf16(vR, h, l);
      Cr[crow * 1024 + o] = h;
      Cr[crow * 1024 + 512 + o] = l;
      split_bf16(vI, h, l);
      Ci[crow * 1024 + o] = h;
      Ci[crow * 1024 + 512 + o] = l;
    }
  }
}

// ---------------- scores = (qr.kr + qi.ki) * SCALE via 3-term split-bf16 MFMA ----------------
__global__ __launch_bounds__(256) void k_scores_mfma(
    const u16* __restrict__ Q_r, const u16* __restrict__ Q_i,
    const u16* __restrict__ K_r, const u16* __restrict__ K_i,
    float* __restrict__ scores) {
  __shared__ u16 sQr[64][LSTR], sQi[64][LSTR], sKr[64][LSTR], sKi[64][LSTR];
  int bm = blockIdx.z;
  int s_blk = blockIdx.y * 64, t_blk = blockIdx.x * 64;
  int tid = threadIdx.x;

  int lrow = tid >> 3;
  int lk8 = (tid & 7) << 3;
  size_t qrow0 = (size_t)(bm * SS + s_blk + lrow), qrow1 = qrow0 + 32;
  size_t krow0 = (size_t)(bm * SS + t_blk + lrow), krow1 = krow0 + 32;

  int wave = tid >> 6, lane = tid & 63;
  int wrow = (wave >> 1) * 32, wcol = (wave & 1) * 32;
  int l31 = lane & 31, khalf = (lane >> 5) * 8;

  f32x16 acc;
  for (int i = 0; i < 16; i++) acc[i] = 0.f;

  for (int it = 0; it < 24; ++it) {
    int seg = it >> 3;
    int k0 = (it & 7) * 64;
    int qofs = (seg == 1) ? 512 : 0;
    int kofs = (seg == 2) ? 512 : 0;
    u16x8 qr0 = *(const u16x8*)&Q_r[qrow0 * 1024 + qofs + k0 + lk8];
    u16x8 qr1 = *(const u16x8*)&Q_r[qrow1 * 1024 + qofs + k0 + lk8];
    u16x8 qi0 = *(const u16x8*)&Q_i[qrow0 * 1024 + qofs + k0 + lk8];
    u16x8 qi1 = *(const u16x8*)&Q_i[qrow1 * 1024 + qofs + k0 + lk8];
    u16x8 kr0 = *(const u16x8*)&K_r[krow0 * 1024 + kofs + k0 + lk8];
    u16x8 kr1 = *(const u16x8*)&K_r[krow1 * 1024 + kofs + k0 + lk8];
    u16x8 ki0 = *(const u16x8*)&K_i[krow0 * 1024 + kofs + k0 + lk8];
    u16x8 ki1 = *(const u16x8*)&K_i[krow1 * 1024 + kofs + k0 + lk8];
    __syncthreads();
    *(u16x8*)&sQr[lrow][lk8] = qr0;
    *(u16x8*)&sQr[lrow + 32][lk8] = qr1;
    *(u16x8*)&sQi[lrow][lk8] = qi0;
    *(u16x8*)&sQi[lrow + 32][lk8] = qi1;
    *(u16x8*)&sKr[lrow][lk8] = kr0;
    *(u16x8*)&sKr[lrow + 32][lk8] = kr1;
    *(u16x8*)&sKi[lrow][lk8] = ki0;
    *(u16x8*)&sKi[lrow + 32][lk8] = ki1;
    __syncthreads();
#pragma unroll
    for (int kk = 0; kk < 64; kk += 16) {
      bf16x8 fQr = *(const bf16x8*)&sQr[wrow + l31][kk + khalf];
      bf16x8 fQi = *(const bf16x8*)&sQi[wrow + l31][kk + khalf];
      bf16x8 fKr = *(const bf16x8*)&sKr[wcol + l31][kk + khalf];
      bf16x8 fKi = *(const bf16x8*)&sKi[wcol + l31][kk + khalf];
      acc = __builtin_amdgcn_mfma_f32_32x32x16_bf16(fQr, fKr, acc, 0, 0, 0);
      acc = __builtin_amdgcn_mfma_f32_32x32x16_bf16(fQi, fKi, acc, 0, 0, 0);
    }
  }

  int t = t_blk + wcol + l31;
#pragma unroll
  for (int reg = 0; reg < 16; reg++) {
    int r_in = (reg & 3) + 8 * (reg >> 2) + 4 * (lane >> 5);
    int s = s_blk + wrow + r_in;
    scores[((size_t)bm * SS + s) * SS + t] = acc[reg] * SCALEF;
  }
}

// ---------------- magnitude LN + phase renorm + mod scale -> split bf16 ----------------
__global__ void k_lnphase(const float* __restrict__ zr, const float* __restrict__ zi,
                          const float* __restrict__ ln_scale, const float* __restrict__ ln_shift,
                          const float* __restrict__ mod_bias,
                          u16* __restrict__ zbr, u16* __restrict__ zbi) {
  int row = blockIdx.x;            // (b*M+m)*S + s
  int m = (row >> 7) & (MM - 1);
  int tid = threadIdx.x;           // 128
  size_t base = (size_t)row * DD;
  float zrv[4], ziv[4], rv[4];
  float sum = 0.f, sumsq = 0.f;
#pragma unroll
  for (int i = 0; i < 4; i++) {
    int o = tid + i * 128;
    float a = zr[base + o], bv = zi[base + o];
    zrv[i] = a; ziv[i] = bv;
    float r = sqrtf(a * a + bv * bv);
    rv[i] = r;
    float mg = r + EPSF;
    sum += mg;
    sumsq += mg * mg;
  }
  __shared__ float rs[128], rq[128];
  rs[tid] = sum; rq[tid] = sumsq;
  __syncthreads();
  for (int off = 64; off > 0; off >>= 1) {
    if (tid < off) { rs[tid] += rs[tid + off]; rq[tid] += rq[tid + off]; }
    __syncthreads();
  }
  float mean = rs[0] * (1.0f / DD);
  float var = (rq[0] - (float)DD * mean * mean) * (1.0f / (DD - 1));
  float inv = 1.0f / sqrtf(var + EPSF);
#pragma unroll
  for (int i = 0; i < 4; i++) {
    int o = tid + i * 128;
    float mg = rv[i] + EPSF;
    float nm = (mg - mean) * inv * ln_scale[m * DD + o] + ln_shift[m * DD + o];
    float r = rv[i];
    float cosp, sinp;
    if (r > 0.f) { cosp = zrv[i] / r; sinp = ziv[i] / r; }
    else { cosp = 1.f; sinp = 0.f; }
    float z1r = nm * cosp, z1i = nm * sinp;
    float nrm = sqrtf(z1r * z1r + z1i * z1i) + EPSF;
    float sc = fmaxf(nrm + mod_bias[m * DD + o], 0.f) / nrm;
    u16 h, l;
    split_bf16(z1r * sc, h, l);
    zbr[(size_t)row * 1024 + o] = h;
    zbr[(size_t)row * 1024 + 512 + o] = l;
    split_bf16(z1i * sc, h, l);
    zbi[(size_t)row * 1024 + o] = h;
    zbi[(size_t)row * 1024 + 512 + o] = l;
  }
}

// ---------------- softmax (inline) + AV + gate + score/conf/halt heads ----------------
__global__ void k_attnav(const float* __restrict__ scores, const float* __restrict__ vr,
                         const float* __restrict__ vi, const float* __restrict__ gate_mask,
                         const float* __restrict__ score_w, const float* __restrict__ score_b,
                         const float* __restrict__ conf_w, const float* __restrict__ conf_b,
                         const float* __restrict__ halt_w, const float* __restrict__ halt_b,
                         float* __restrict__ pr, float* __restrict__ pi,
                         float* __restrict__ score, float* __restrict__ conf,
                         float* __restrict__ halt) {
  int row = blockIdx.x;           // (b*M+m)*S + s
  int bm = row >> 7;
  int m = bm & (MM - 1);
  int tid = threadIdx.x;          // 256
  __shared__ float att[SS];
  __shared__ float sbuf[128];
  __shared__ float r0[256], r1[256], r2[256];

  // inline row softmax over 128
  float v = 0.f;
  if (tid < SS) { v = scores[(size_t)row * SS + tid]; sbuf[tid] = v; }
  __syncthreads();
  for (int off = 64; off > 0; off >>= 1) {
    if (tid < off) sbuf[tid] = fmaxf(sbuf[tid], sbuf[tid + off]);
    __syncthreads();
  }
  float mx = sbuf[0];
  __syncthreads();
  float e = 0.f;
  if (tid < SS) { e = expf(v - mx); sbuf[tid] = e; }
  __syncthreads();
  for (int off = 64; off > 0; off >>= 1) {
    if (tid < off) sbuf[tid] += sbuf[tid + off];
    __syncthreads();
  }
  float ssum = sbuf[0];
  __syncthreads();
  if (tid < SS) att[tid] = e / ssum;
  __syncthreads();

  size_t vbase = (size_t)bm * SS * DD;
  float sp = 0.f, cp = 0.f, hp = 0.f;
#pragma unroll
  for (int i = 0; i < 2; i++) {
    int d = tid + i * 256;
    float aR = 0.f, aI = 0.f;
    for (int t = 0; t < SS; t++) {
      float a = att[t];
      aR += a * vr[vbase + (size_t)t * DD + d];
      aI += a * vi[vbase + (size_t)t * DD + d];
    }
    float g = 1.f / (1.f + expf(-gate_mask[m * DD + d]));
    float pR = aR * g, pI = aI * g;
    pr[(size_t)row * DD + d] = pR;
    pi[(size_t)row * DD + d] = pI;
    sp += pR * score_w[m * 2 * DD + d] + pI * score_w[m * 2 * DD + DD + d];
    cp += pR * conf_w[m * 2 * DD + d] + pI * conf_w[m * 2 * DD + DD + d];
    hp += pR * halt_w[m * 2 * DD + d] + pI * halt_w[m * 2 * DD + DD + d];
  }
  r0[tid] = sp; r1[tid] = cp; r2[tid] = hp;
  __syncthreads();
  for (int off = 128; off > 0; off >>= 1) {
    if (tid < off) { r0[tid] += r0[tid + off]; r1[tid] += r1[tid + off]; r2[tid] += r2[tid + off]; }
    __syncthreads();
  }
  if (tid == 0) {
    score[row] = r0[0] + score_b[m];
    conf[row] = 1.f / (1.f + expf(-(r1[0] + conf_b[m])));
    halt[row] = r2[0] + halt_b[m];
  }
}

// ---------------- stack mem update + read + st dot partials (16 blocks) ----------------
__global__ void k_memup(const float* __restrict__ flat_in,
                        const float* __restrict__ nptrg, const float* __restrict__ wmg,
                        float* __restrict__ memv, float* __restrict__ readv,
                        const float* __restrict__ st_score_w, const float* __restrict__ st_conf_w,
                        float* __restrict__ stacc) {
  int b = blockIdx.x >> 2;
  int chunk = blockIdx.x & 3;
  int tid = threadIdx.x;           // 256
  int e = chunk * 256 + tid;       // 0..1023
  __shared__ float nptr[KK], wm[KK];
  __shared__ float red[256], red2[256];
  if (tid < KK) { nptr[tid] = nptrg[b * KK + tid]; wm[tid] = wmg[b * KK + tid]; }
  __syncthreads();
  float fl = flat_in[b * 2 * DD + e];
  float racc = 0.f;
#pragma unroll
  for (int k = 0; k < KK; k++) {
    size_t idx = ((size_t)(b * KK + k)) * 2 * DD + e;
    float nm = wm[k] * fl + memv[idx] * (1.f - wm[k]);
    memv[idx] = nm;
    racc += nm * nptr[k];
  }
  readv[b * 2 * DD + e] = racc;
  red[tid] = racc * st_score_w[e];
  red2[tid] = racc * st_conf_w[e];
  __syncthreads();
  for (int off = 128; off > 0; off >>= 1) {
    if (tid < off) { red[tid] += red[tid + off]; red2[tid] += red2[tid + off]; }
    __syncthreads();
  }
  if (tid == 0) {
    atomicAdd(&stacc[b * 2], red[0]);
    atomicAdd(&stacc[b * 2 + 1], red2[0]);
  }
}

// ---------------- halt p + stv finalize ----------------
__global__ void k_haltp(const float* __restrict__ halt, float* __restrict__ rem,
                        float* __restrict__ coeff, const float* __restrict__ stacc,
                        const float* __restrict__ st_score_b, const float* __restrict__ st_conf_b,
                        float* __restrict__ stv) {
  int b = blockIdx.x;
  int tid = threadIdx.x;  // 256
  __shared__ float red[256];
  float v0 = halt[b * MM * SS + tid];
  float v1 = halt[b * MM * SS + 256 + tid];
  red[tid] = 1.f / (1.f + expf(-v0)) + 1.f / (1.f + expf(-v1));
  __syncthreads();
  for (int off = 128; off > 0; off >>= 1) {
    if (tid < off) red[tid] += red[tid + off];
    __syncthreads();
  }
  if (tid == 0) {
    float p = red[0] * (1.0f / (MM * SS));
    float r = rem[b];
    coeff[b] = p * r;
    rem[b] = r * (1.f - p);
    stv[b] = stacc[b * 2] + st_score_b[0];
    stv[BB + b] = 1.f / (1.f + expf(-(stacc[b * 2 + 1] + st_conf_b[0])));
  }
}

// ---------------- module-mix softmax + new state + acc + next-step c (split) ----------------
__global__ void k_combine(const float* __restrict__ pr, const float* __restrict__ pi,
                          const float* __restrict__ score, const float* __restrict__ conf,
                          const float* __restrict__ stv, const float* __restrict__ readv,
                          const float* __restrict__ coeff,
                          const float* __restrict__ xr, const float* __restrict__ xi,
                          float* __restrict__ sr, float* __restrict__ si, float* __restrict__ acc,
                          u16* __restrict__ crbf, u16* __restrict__ cibf) {
  int bs = blockIdx.x;             // b*S + s
  int b = bs >> 7, s = bs & (SS - 1);
  int tid = threadIdx.x;           // 256
  __shared__ float w[5];
  if (tid == 0) {
    float l[5];
    for (int m = 0; m < MM; m++) {
      int r = (b * MM + m) * SS + s;
      l[m] = score[r] * conf[r];
    }
    l[4] = stv[b] * stv[BB + b];
    float mx = l[0];
    for (int j = 1; j < 5; j++) mx = fmaxf(mx, l[j]);
    float sum = 0.f;
    for (int j = 0; j < 5; j++) { l[j] = expf(l[j] - mx); sum += l[j]; }
    for (int j = 0; j < 5; j++) w[j] = l[j] / sum;
  }
  __syncthreads();
  float cf = coeff[b];
#pragma unroll
  for (int i = 0; i < 2; i++) {
    int d = tid + i * 256;
    float nsr = w[4] * readv[b * 2 * DD + d];
    float nsi = w[4] * readv[b * 2 * DD + DD + d];
#pragma unroll
    for (int m = 0; m < MM; m++) {
      size_t off = ((size_t)((b * MM + m) * SS + s)) * DD + d;
      nsr += w[m] * pr[off];
      nsi += w[m] * pi[off];
    }
    size_t sidx = (size_t)bs * DD + d;
    sr[sidx] = nsr;
    si[sidx] = nsi;
    size_t aoff = (size_t)bs * 2 * DD;
    acc[aoff + d] += cf * nsr;
    acc[aoff + DD + d] += cf * nsi;
    // next-step c = 0.5x + 0.5s, split bf16
    u16 h, l;
    split_bf16(0.5f * xr[sidx] + 0.5f * nsr, h, l);
    crbf[(size_t)bs * 1024 + d] = h;
    crbf[(size_t)bs * 1024 + 512 + d] = l;
    split_bf16(0.5f * xi[sidx] + 0.5f * nsi, h, l);
    cibf[(size_t)bs * 1024 + d] = h;
    cibf[(size_t)bs * 1024 + 512 + d] = l;
  }
}

// ---------------- out = acc + rem * concat(sr, si) ----------------
__global__ void k_final(const float* __restrict__ acc, const float* __restrict__ rem,
                        const float* __restrict__ sr, const float* __restrict__ si,
                        float* __restrict__ out) {
  int idx = blockIdx.x * 256 + threadIdx.x;  // < B*S*2D
  int e = idx & (2 * DD - 1);
  int bs = idx >> 10;
  int b = bs >> 7;
  float v = (e < DD) ? sr[(size_t)bs * DD + e] : si[(size_t)bs * DD + e - DD];
  out[idx] = acc[idx] + rem[b] * v;
}

extern "C" void kernel_launch(void* const* d_in, const int* in_sizes, int n_in,
                              void* d_out, int out_size, void* d_ws, size_t ws_size,
                              hipStream_t stream) {
  const float* xr = (const float*)d_in[0];
  const float* xi = (const float*)d_in[1];
  const float* Wl_r = (const float*)d_in[2];
  const float* Wl_i = (const float*)d_in[3];
  const float* Wq_r = (const float*)d_in[4];
  const float* Wq_i = (const float*)d_in[5];
  const float* Wk_r = (const float*)d_in[6];
  const float* Wk_i = (const float*)d_in[7];
  const float* Wv_r = (const float*)d_in[8];
  const float* Wv_i = (const float*)d_in[9];
  const float* ln_scale = (const float*)d_in[10];
  const float* ln_shift = (const float*)d_in[11];
  const float* mod_bias = (const float*)d_in[12];
  const float* gate_mask = (const float*)d_in[13];
  const float* score_w = (const float*)d_in[14];
  const float* score_b = (const float*)d_in[15];
  const float* conf_w = (const float*)d_in[16];
  const float* conf_b = (const float*)d_in[17];
  const float* halt_w = (const float*)d_in[18];
  const float* halt_b = (const float*)d_in[19];
  const float* ctrl_w = (const float*)d_in[20];
  const float* ctrl_b = (const float*)d_in[21];
  const float* st_score_w = (const float*)d_in[22];
  const float* st_score_b = (const float*)d_in[23];
  const float* st_conf_w = (const float*)d_in[24];
  const float* st_conf_b = (const float*)d_in[25];
  float* out = (float*)d_out;

  const int BSD = BB * SS * DD;        // 262144
  const int BMSD = BB * MM * SS * DD;  // 1048576
  const size_t WSLOT = (size_t)MM * DD * 1024;  // 2097152 u16 per weight matrix

  char* pc = (char*)d_ws;
  float* sr = (float*)pc; pc += (size_t)BSD * 4;
  float* si = (float*)pc; pc += (size_t)BSD * 4;
  float* zr = (float*)pc; pc += (size_t)BMSD * 4;
  float* zi = (float*)pc; pc += (size_t)BMSD * 4;
  float* vr = (float*)pc; pc += (size_t)BMSD * 4;
  float* vi = (float*)pc; pc += (size_t)BMSD * 4;
  float* prb = (float*)pc; pc += (size_t)BMSD * 4;
  float* pib = (float*)pc; pc += (size_t)BMSD * 4;
  float* scoresb = (float*)pc; pc += (size_t)BB * MM * SS * SS * 4;
  float* scorev = (float*)pc; pc += (size_t)BB * MM * SS * 4;
  float* confv = (float*)pc; pc += (size_t)BB * MM * SS * 4;
  float* haltv = (float*)pc; pc += (size_t)BB * MM * SS * 4;
  float* flat = (float*)pc; pc += (size_t)BB * 2 * DD * 4;
  float* stacc = (float*)pc; pc += 64;
  float* nptrg = (float*)pc; pc += (size_t)BB * KK * 4;
  float* wmg = (float*)pc; pc += (size_t)BB * KK * 4;
  float* memv = (float*)pc; pc += (size_t)BB * KK * 2 * DD * 4;
  float* ptrv = (float*)pc; pc += (size_t)BB * KK * 4;
  float* readv = (float*)pc; pc += (size_t)BB * 2 * DD * 4;
  float* stv = (float*)pc; pc += (size_t)2 * BB * 4;
  float* accb = (float*)pc; pc += (size_t)BB * SS * 2 * DD * 4;
  float* rem = (float*)pc; pc += (size_t)BB * 4;
  float* coeff = (float*)pc; pc += (size_t)BB * 4;
  u16* crbf = (u16*)pc; pc += (size_t)BB * SS * 1024 * 2;
  u16* cibf = (u16*)pc; pc += (size_t)BB * SS * 1024 * 2;
  u16* zbr = (u16*)pc; pc += (size_t)BB * MM * SS * 1024 * 2;
  u16* zbi = (u16*)pc; pc += (size_t)BB * MM * SS * 1024 * 2;
  u16* qbr = (u16*)pc; pc += (size_t)BB * MM * SS * 1024 * 2;
  u16* qbi = (u16*)pc; pc += (size_t)BB * MM * SS * 1024 * 2;
  u16* kbr = (u16*)pc; pc += (size_t)BB * MM * SS * 1024 * 2;
  u16* kbi = (u16*)pc; pc += (size_t)BB * MM * SS * 1024 * 2;
  u16* wbf = (u16*)pc; pc += 8 * WSLOT * 2;  // Wl_r,Wl_i,Wq_r,Wq_i,Wk_r,Wk_i,Wv_r,Wv_i

  // one-time (per launch) weight conversion
  k_convw<<<4096, 256, 0, stream>>>(Wl_r, wbf + 0 * WSLOT);
  k_convw<<<4096, 256, 0, stream>>>(Wl_i, wbf + 1 * WSLOT);
  k_convw<<<4096, 256, 0, stream>>>(Wq_r, wbf + 2 * WSLOT);
  k_convw<<<4096, 256, 0, stream>>>(Wq_i, wbf + 3 * WSLOT);
  k_convw<<<4096, 256, 0, stream>>>(Wk_r, wbf + 4 * WSLOT);
  k_convw<<<4096, 256, 0, stream>>>(Wk_i, wbf + 5 * WSLOT);
  k_convw<<<4096, 256, 0, stream>>>(Wv_r, wbf + 6 * WSLOT);
  k_convw<<<4096, 256, 0, stream>>>(Wv_i, wbf + 7 * WSLOT);

  k_init<<<2048, 256, 0, stream>>>(xr, xi, sr, si, accb, memv, ptrv, rem, crbf, cibf);

  dim3 ggrid(DD / 64, (BB * SS) / 64, MM);        // (8, 8, 4)   = 256 blocks
  dim3 qgrid(DD / 64, (BB * SS) / 64, MM * 3);    // (8, 8, 12)  = 768 blocks
  dim3 sgrid(SS / 64, SS / 64, BB * MM);          // (2, 2, 16)  = 64 blocks

  for (int step = 0; step < NSTEPS; ++step) {
    k_flatctrl<<<BB, 256, 0, stream>>>(sr, si, ctrl_w, ctrl_b, ptrv, flat, nptrg, wmg, stacc);
    k_gemm_mfma<<<ggrid, 256, 0, stream>>>(crbf, cibf, wbf + 0 * WSLOT, wbf + 1 * WSLOT, zr, zi);
    k_lnphase<<<BB * MM * SS, 128, 0, stream>>>(zr, zi, ln_scale, ln_shift, mod_bias, zbr, zbi);
    k_gemm_qkv<<<qgrid, 256, 0, stream>>>(zbr, zbi, wbf, WSLOT, qbr, qbi, kbr, kbi, vr, vi);
    k_scores_mfma<<<sgrid, 256, 0, stream>>>(qbr, qbi, kbr, kbi, scoresb);
    k_attnav<<<BB * MM * SS, 256, 0, stream>>>(scoresb, vr, vi, gate_mask, score_w, score_b,
                                               conf_w, conf_b, halt_w, halt_b,
                                               prb, pib, scorev, confv, haltv);
    k_memup<<<BB * 4, 256, 0, stream>>>(flat, nptrg, wmg, memv, readv,
                                        st_score_w, st_conf_w, stacc);
    k_haltp<<<BB, 256, 0, stream>>>(haltv, rem, coeff, stacc, st_score_b, st_conf_b, stv);
    k_combine<<<BB * SS, 256, 0, stream>>>(prb, pib, scorev, confv, stv, readv, coeff,
                                           xr, xi, sr, si, accb, crbf, cibf);
  }

  k_final<<<(BB * SS * 2 * DD) / 256, 256, 0, stream>>>(accb, rem, sr, si, out);
}

// Round 6
// 2396.962 us; speedup vs baseline: 21.6191x; 1.2185x over previous
//
#include <hip/hip_runtime.h>

#define DD 512
#define MM 4
#define BB 4
#define SS 128
#define KK 32
#define NSTEPS 16
#define EPSF 1e-6f
#define SCALEF 0.04419417382415922f  // 512^-0.5

typedef unsigned short u16;
typedef __bf16 bf16x8 __attribute__((ext_vector_type(8)));
typedef u16 u16x8 __attribute__((ext_vector_type(8)));
typedef float f32x16 __attribute__((ext_vector_type(16)));

__device__ inline void split_bf16(float x, u16& h, u16& l) {
  __bf16 hb = (__bf16)x;
  float hf = (float)hb;
  __bf16 lb = (__bf16)(x - hf);
  h = __builtin_bit_cast(u16, hb);
  l = __builtin_bit_cast(u16, lb);
}

// ---------------- weight fp32 -> split bf16 [row][1024] (hi | lo) ----------------
__global__ void k_convw(const float* __restrict__ src, u16* __restrict__ dst) {
  int idx = blockIdx.x * 256 + threadIdx.x;  // over M*D*D
  int row = idx >> 9, k = idx & 511;
  u16 h, l;
  split_bf16(src[idx], h, l);
  dst[(size_t)row * 1024 + k] = h;
  dst[(size_t)row * 1024 + 512 + k] = l;
}

// ---------------- init ----------------
__global__ void k_init(const float* __restrict__ xr, const float* __restrict__ xi,
                       float* __restrict__ sr, float* __restrict__ si,
                       float* __restrict__ acc, float* __restrict__ memv,
                       float* __restrict__ ptrv, float* __restrict__ rem,
                       u16* __restrict__ crbf, u16* __restrict__ cibf) {
  int idx = blockIdx.x * 256 + threadIdx.x;
  if (idx < BB * SS * 2 * DD) acc[idx] = 0.f;
  if (idx < BB * SS * DD) {
    float a = xr[idx], b = xi[idx];
    sr[idx] = a; si[idx] = b;
    int row = idx >> 9, d = idx & 511;
    u16 h, l;
    split_bf16(a, h, l);   // c0 = 0.5x + 0.5x = x
    crbf[(size_t)row * 1024 + d] = h;
    crbf[(size_t)row * 1024 + 512 + d] = l;
    split_bf16(b, h, l);
    cibf[(size_t)row * 1024 + d] = h;
    cibf[(size_t)row * 1024 + 512 + d] = l;
  }
  if (idx < BB * KK * 2 * DD) memv[idx] = 0.f;
  if (idx < BB * KK) ptrv[idx] = ((idx & (KK - 1)) == 0) ? 1.f : 0.f;
  if (idx < BB) rem[idx] = 1.f;
}

// ---------------- flat_in + control softmax + ptr update ----------------
__global__ void k_flatctrl(const float* __restrict__ sr, const float* __restrict__ si,
                           const float* __restrict__ ctrl_w, const float* __restrict__ ctrl_b,
                           float* __restrict__ ptrv, float* __restrict__ flat_in,
                           float* __restrict__ nptrg, float* __restrict__ wmg,
                           float* __restrict__ stacc) {
  int b = blockIdx.x;
  int tid = threadIdx.x;  // 256
  __shared__ float red[3 * 256];
  __shared__ float ctrl[3], optr[KK], nptr_s[KK], wm_s[KK], normf;

  if (tid < KK) optr[tid] = ptrv[b * KK + tid];

  int e4 = tid * 4;
  const float* basep = (e4 < DD) ? sr : si;
  int d4 = (e4 < DD) ? e4 : (e4 - DD);
  float4 accv = make_float4(0.f, 0.f, 0.f, 0.f);
  size_t base = (size_t)b * SS * DD + d4;
  for (int s = 0; s < SS; s++) {
    float4 v = *(const float4*)&basep[base + (size_t)s * DD];
    accv.x += v.x; accv.y += v.y; accv.z += v.z; accv.w += v.w;
  }
  accv.x *= (1.0f / SS); accv.y *= (1.0f / SS); accv.z *= (1.0f / SS); accv.w *= (1.0f / SS);
  *(float4*)&flat_in[b * 2 * DD + e4] = accv;
  float fv[4] = {accv.x, accv.y, accv.z, accv.w};
  float d0 = 0.f, d1 = 0.f, d2 = 0.f;
#pragma unroll
  for (int j = 0; j < 4; j++) {
    d0 += fv[j] * ctrl_w[(e4 + j) * 3 + 0];
    d1 += fv[j] * ctrl_w[(e4 + j) * 3 + 1];
    d2 += fv[j] * ctrl_w[(e4 + j) * 3 + 2];
  }
  red[tid] = d0; red[256 + tid] = d1; red[512 + tid] = d2;
  __syncthreads();
  for (int off = 128; off > 0; off >>= 1) {
    if (tid < off) {
      red[tid] += red[tid + off];
      red[256 + tid] += red[256 + tid + off];
      red[512 + tid] += red[512 + tid + off];
    }
    __syncthreads();
  }
  if (tid == 0) {
    float l0 = red[0] + ctrl_b[0], l1 = red[256] + ctrl_b[1], l2 = red[512] + ctrl_b[2];
    float mx = fmaxf(l0, fmaxf(l1, l2));
    float e0 = expf(l0 - mx), e1 = expf(l1 - mx), e2 = expf(l2 - mx);
    float s = e0 + e1 + e2;
    ctrl[0] = e0 / s; ctrl[1] = e1 / s; ctrl[2] = e2 / s;
    stacc[b * 2] = 0.f; stacc[b * 2 + 1] = 0.f;
  }
  __syncthreads();
  if (tid < KK) {
    float up = optr[(tid + KK - 1) & (KK - 1)];
    float dn = optr[(tid + 1) & (KK - 1)];
    float cu = optr[tid];
    nptr_s[tid] = ctrl[0] * up + ctrl[1] * dn + ctrl[2] * cu;
    wm_s[tid] = ctrl[0] * up;
  }
  __syncthreads();
  if (tid == 0) {
    float s = 0.f;
    for (int k = 0; k < KK; k++) s += nptr_s[k];
    normf = 1.f / (s + EPSF);
  }
  __syncthreads();
  if (tid < KK) {
    float np = nptr_s[tid] * normf;
    ptrv[b * KK + tid] = np;
    nptrg[b * KK + tid] = np;
    wmg[b * KK + tid] = wm_s[tid];
  }
}

#define LSTR 72  // LDS row stride in bf16 elems

// ---------------- Wl complex NT GEMM, software-pipelined (fp32 out) ----------------
__global__ __launch_bounds__(256) void k_gemm_mfma(
    const u16* __restrict__ Ar, const u16* __restrict__ Ai,
    const u16* __restrict__ Wr, const u16* __restrict__ Wi,
    float* __restrict__ Cr, float* __restrict__ Ci) {
  __shared__ u16 sAr[64][LSTR], sAi[64][LSTR], sWr[64][LSTR], sWi[64][LSTR];
  int m = blockIdx.z;
  int row_blk = blockIdx.y * 64, o_blk = blockIdx.x * 64;
  int tid = threadIdx.x;

  int lrow = tid >> 3, lk8 = (tid & 7) << 3;
  size_t arow0 = (size_t)(row_blk + lrow), arow1 = arow0 + 32;  // dense b*S+s rows
  size_t wrow0 = (size_t)m * DD + o_blk + lrow, wrow1 = wrow0 + 32;

  int wave = tid >> 6, lane = tid & 63;
  int wrow = (wave >> 1) * 32, wcol = (wave & 1) * 32;
  int l31 = lane & 31, khalf = (lane >> 5) * 8;

  f32x16 accP, accN, accI;
  for (int i = 0; i < 16; i++) { accP[i] = 0.f; accN[i] = 0.f; accI[i] = 0.f; }

  // prologue loads (it=0: seg0, k0=0)
  u16x8 g0 = *(const u16x8*)&Ar[arow0 * 1024 + lk8];
  u16x8 g1 = *(const u16x8*)&Ar[arow1 * 1024 + lk8];
  u16x8 g2 = *(const u16x8*)&Ai[arow0 * 1024 + lk8];
  u16x8 g3 = *(const u16x8*)&Ai[arow1 * 1024 + lk8];
  u16x8 g4 = *(const u16x8*)&Wr[wrow0 * 1024 + lk8];
  u16x8 g5 = *(const u16x8*)&Wr[wrow1 * 1024 + lk8];
  u16x8 g6 = *(const u16x8*)&Wi[wrow0 * 1024 + lk8];
  u16x8 g7 = *(const u16x8*)&Wi[wrow1 * 1024 + lk8];

  for (int it = 0; it < 24; ++it) {
    __syncthreads();  // prev iter's LDS reads complete
    *(u16x8*)&sAr[lrow][lk8] = g0;
    *(u16x8*)&sAr[lrow + 32][lk8] = g1;
    *(u16x8*)&sAi[lrow][lk8] = g2;
    *(u16x8*)&sAi[lrow + 32][lk8] = g3;
    *(u16x8*)&sWr[lrow][lk8] = g4;
    *(u16x8*)&sWr[lrow + 32][lk8] = g5;
    *(u16x8*)&sWi[lrow][lk8] = g6;
    *(u16x8*)&sWi[lrow + 32][lk8] = g7;
    // issue next iter's loads BEFORE compute (hide latency behind MFMA)
    u16x8 n0, n1, n2, n3, n4, n5, n6, n7;
    if (it < 23) {
      int it2 = it + 1, seg = it2 >> 3, k0 = (it2 & 7) * 64;
      int aofs = (seg == 1) ? 512 : 0, wofs = (seg == 2) ? 512 : 0;
      n0 = *(const u16x8*)&Ar[arow0 * 1024 + aofs + k0 + lk8];
      n1 = *(const u16x8*)&Ar[arow1 * 1024 + aofs + k0 + lk8];
      n2 = *(const u16x8*)&Ai[arow0 * 1024 + aofs + k0 + lk8];
      n3 = *(const u16x8*)&Ai[arow1 * 1024 + aofs + k0 + lk8];
      n4 = *(const u16x8*)&Wr[wrow0 * 1024 + wofs + k0 + lk8];
      n5 = *(const u16x8*)&Wr[wrow1 * 1024 + wofs + k0 + lk8];
      n6 = *(const u16x8*)&Wi[wrow0 * 1024 + wofs + k0 + lk8];
      n7 = *(const u16x8*)&Wi[wrow1 * 1024 + wofs + k0 + lk8];
    }
    __syncthreads();
#pragma unroll
    for (int kk = 0; kk < 64; kk += 16) {
      bf16x8 fAr = *(const bf16x8*)&sAr[wrow + l31][kk + khalf];
      bf16x8 fAi = *(const bf16x8*)&sAi[wrow + l31][kk + khalf];
      bf16x8 fWr = *(const bf16x8*)&sWr[wcol + l31][kk + khalf];
      bf16x8 fWi = *(const bf16x8*)&sWi[wcol + l31][kk + khalf];
      accP = __builtin_amdgcn_mfma_f32_32x32x16_bf16(fAr, fWr, accP, 0, 0, 0);
      accN = __builtin_amdgcn_mfma_f32_32x32x16_bf16(fAi, fWi, accN, 0, 0, 0);
      accI = __builtin_amdgcn_mfma_f32_32x32x16_bf16(fAi, fWr, accI, 0, 0, 0);
      accI = __builtin_amdgcn_mfma_f32_32x32x16_bf16(fAr, fWi, accI, 0, 0, 0);
    }
    if (it < 23) {
      g0 = n0; g1 = n1; g2 = n2; g3 = n3; g4 = n4; g5 = n5; g6 = n6; g7 = n7;
    }
  }

  int o = o_blk + wcol + l31;
#pragma unroll
  for (int reg = 0; reg < 16; reg++) {
    int r_in = (reg & 3) + 8 * (reg >> 2) + 4 * (lane >> 5);
    int gr = row_blk + wrow + r_in;
    int b = gr >> 7, s = gr & (SS - 1);
    size_t crow = (size_t)((b * MM + m) * SS + s);
    Cr[crow * DD + o] = accP[reg] - accN[reg];
    Ci[crow * DD + o] = accI[reg];
  }
}

// ---------------- merged Q/K/V GEMM, software-pipelined; all outputs split u16 ----------------
__global__ __launch_bounds__(256) void k_gemm_qkv(
    const u16* __restrict__ Ar, const u16* __restrict__ Ai,
    const u16* __restrict__ wbf, size_t WSLOT,
    u16* __restrict__ qbr, u16* __restrict__ qbi,
    u16* __restrict__ kbr, u16* __restrict__ kbi,
    u16* __restrict__ vbr, u16* __restrict__ vbi) {
  __shared__ u16 sAr[64][LSTR], sAi[64][LSTR], sWr[64][LSTR], sWi[64][LSTR];
  int zid = blockIdx.z;
  int m = zid / 3, w = zid - 3 * m;
  const u16* Wr = wbf + (size_t)(2 + 2 * w) * WSLOT;
  const u16* Wi = Wr + WSLOT;
  int row_blk = blockIdx.y * 64, o_blk = blockIdx.x * 64;
  int tid = threadIdx.x;

  int lrow = tid >> 3, lk8 = (tid & 7) << 3;
  int gr0 = row_blk + lrow, gr1 = gr0 + 32;
  size_t arow0 = (size_t)(((gr0 >> 7) * MM + m) * SS + (gr0 & (SS - 1)));
  size_t arow1 = (size_t)(((gr1 >> 7) * MM + m) * SS + (gr1 & (SS - 1)));
  size_t wrow0 = (size_t)m * DD + o_blk + lrow, wrow1 = wrow0 + 32;

  int wave = tid >> 6, lane = tid & 63;
  int wrow = (wave >> 1) * 32, wcol = (wave & 1) * 32;
  int l31 = lane & 31, khalf = (lane >> 5) * 8;

  f32x16 accP, accN, accI;
  for (int i = 0; i < 16; i++) { accP[i] = 0.f; accN[i] = 0.f; accI[i] = 0.f; }

  u16x8 g0 = *(const u16x8*)&Ar[arow0 * 1024 + lk8];
  u16x8 g1 = *(const u16x8*)&Ar[arow1 * 1024 + lk8];
  u16x8 g2 = *(const u16x8*)&Ai[arow0 * 1024 + lk8];
  u16x8 g3 = *(const u16x8*)&Ai[arow1 * 1024 + lk8];
  u16x8 g4 = *(const u16x8*)&Wr[wrow0 * 1024 + lk8];
  u16x8 g5 = *(const u16x8*)&Wr[wrow1 * 1024 + lk8];
  u16x8 g6 = *(const u16x8*)&Wi[wrow0 * 1024 + lk8];
  u16x8 g7 = *(const u16x8*)&Wi[wrow1 * 1024 + lk8];

  for (int it = 0; it < 24; ++it) {
    __syncthreads();
    *(u16x8*)&sAr[lrow][lk8] = g0;
    *(u16x8*)&sAr[lrow + 32][lk8] = g1;
    *(u16x8*)&sAi[lrow][lk8] = g2;
    *(u16x8*)&sAi[lrow + 32][lk8] = g3;
    *(u16x8*)&sWr[lrow][lk8] = g4;
    *(u16x8*)&sWr[lrow + 32][lk8] = g5;
    *(u16x8*)&sWi[lrow][lk8] = g6;
    *(u16x8*)&sWi[lrow + 32][lk8] = g7;
    u16x8 n0, n1, n2, n3, n4, n5, n6, n7;
    if (it < 23) {
      int it2 = it + 1, seg = it2 >> 3, k0 = (it2 & 7) * 64;
      int aofs = (seg == 1) ? 512 : 0, wofs = (seg == 2) ? 512 : 0;
      n0 = *(const u16x8*)&Ar[arow0 * 1024 + aofs + k0 + lk8];
      n1 = *(const u16x8*)&Ar[arow1 * 1024 + aofs + k0 + lk8];
      n2 = *(const u16x8*)&Ai[arow0 * 1024 + aofs + k0 + lk8];
      n3 = *(const u16x8*)&Ai[arow1 * 1024 + aofs + k0 + lk8];
      n4 = *(const u16x8*)&Wr[wrow0 * 1024 + wofs + k0 + lk8];
      n5 = *(const u16x8*)&Wr[wrow1 * 1024 + wofs + k0 + lk8];
      n6 = *(const u16x8*)&Wi[wrow0 * 1024 + wofs + k0 + lk8];
      n7 = *(const u16x8*)&Wi[wrow1 * 1024 + wofs + k0 + lk8];
    }
    __syncthreads();
#pragma unroll
    for (int kk = 0; kk < 64; kk += 16) {
      bf16x8 fAr = *(const bf16x8*)&sAr[wrow + l31][kk + khalf];
      bf16x8 fAi = *(const bf16x8*)&sAi[wrow + l31][kk + khalf];
      bf16x8 fWr = *(const bf16x8*)&sWr[wcol + l31][kk + khalf];
      bf16x8 fWi = *(const bf16x8*)&sWi[wcol + l31][kk + khalf];
      accP = __builtin_amdgcn_mfma_f32_32x32x16_bf16(fAr, fWr, accP, 0, 0, 0);
      accN = __builtin_amdgcn_mfma_f32_32x32x16_bf16(fAi, fWi, accN, 0, 0, 0);
      accI = __builtin_amdgcn_mfma_f32_32x32x16_bf16(fAi, fWr, accI, 0, 0, 0);
      accI = __builtin_amdgcn_mfma_f32_32x32x16_bf16(fAr, fWi, accI, 0, 0, 0);
    }
    if (it < 23) {
      g0 = n0; g1 = n1; g2 = n2; g3 = n3; g4 = n4; g5 = n5; g6 = n6; g7 = n7;
    }
  }

  u16* Cr = (w == 0) ? qbr : ((w == 1) ? kbr : vbr);
  u16* Ci = (w == 0) ? qbi : ((w == 1) ? kbi : vbi);
  int o = o_blk + wcol + l31;
#pragma unroll
  for (int reg = 0; reg < 16; reg++) {
    int r_in = (reg & 3) + 8 * (reg >> 2) + 4 * (lane >> 5);
    int gr = row_blk + wrow + r_in;
    int b = gr >> 7, s = gr & (SS - 1);
    size_t crow = (size_t)((b * MM + m) * SS + s);
    u16 h, l;
    split_bf16(accP[reg] - accN[reg], h, l);
    Cr[crow * 1024 + o] = h;
    Cr[crow * 1024 + 512 + o] = l;
    split_bf16(accI[reg], h, l);
    Ci[crow * 1024 + o] = h;
    Ci[crow * 1024 + 512 + o] = l;
  }
}

// ---------------- scores (64 rows x 128 cols per block) + fused softmax -> split P ----------------
__global__ __launch_bounds__(256) void k_scores_sm(
    const u16* __restrict__ Q_r, const u16* __restrict__ Q_i,
    const u16* __restrict__ K_r, const u16* __restrict__ K_i,
    u16* __restrict__ Pb) {
  __shared__ __align__(16) char smem[55296];  // 54 KB
  u16 (*sQr)[LSTR] = (u16(*)[LSTR])smem;                  // 64 rows
  u16 (*sQi)[LSTR] = (u16(*)[LSTR])(smem + 9216);         // 64 rows
  u16 (*sKr)[LSTR] = (u16(*)[LSTR])(smem + 18432);        // 128 rows
  u16 (*sKi)[LSTR] = (u16(*)[LSTR])(smem + 36864);        // 128 rows
  float (*stile)[132] = (float(*)[132])smem;              // 64 x 132 overlay (33792 B)

  int bm = blockIdx.z;
  int s_blk = blockIdx.y * 64;
  int tid = threadIdx.x;
  int lrow = tid >> 3, lk8 = (tid & 7) << 3;
  size_t qrow0 = (size_t)(bm * SS + s_blk + lrow), qrow1 = qrow0 + 32;
  size_t krow = (size_t)(bm * SS + lrow);  // +0,32,64,96

  int wave = tid >> 6, lane = tid & 63;
  int srow_w = (wave & 1) * 32;
  int tcol_w = (wave >> 1) * 64;
  int l31 = lane & 31, khalf = (lane >> 5) * 8;

  f32x16 acc0, acc1;
  for (int i = 0; i < 16; i++) { acc0[i] = 0.f; acc1[i] = 0.f; }

  for (int it = 0; it < 24; ++it) {
    int seg = it >> 3, k0 = (it & 7) * 64;
    int qofs = (seg == 1) ? 512 : 0;
    int kofs = (seg == 2) ? 512 : 0;
    u16x8 q0 = *(const u16x8*)&Q_r[qrow0 * 1024 + qofs + k0 + lk8];
    u16x8 q1 = *(const u16x8*)&Q_r[qrow1 * 1024 + qofs + k0 + lk8];
    u16x8 q2 = *(const u16x8*)&Q_i[qrow0 * 1024 + qofs + k0 + lk8];
    u16x8 q3 = *(const u16x8*)&Q_i[qrow1 * 1024 + qofs + k0 + lk8];
    u16x8 kr0 = *(const u16x8*)&K_r[(krow + 0) * 1024 + kofs + k0 + lk8];
    u16x8 kr1 = *(const u16x8*)&K_r[(krow + 32) * 1024 + kofs + k0 + lk8];
    u16x8 kr2 = *(const u16x8*)&K_r[(krow + 64) * 1024 + kofs + k0 + lk8];
    u16x8 kr3 = *(const u16x8*)&K_r[(krow + 96) * 1024 + kofs + k0 + lk8];
    u16x8 ki0 = *(const u16x8*)&K_i[(krow + 0) * 1024 + kofs + k0 + lk8];
    u16x8 ki1 = *(const u16x8*)&K_i[(krow + 32) * 1024 + kofs + k0 + lk8];
    u16x8 ki2 = *(const u16x8*)&K_i[(krow + 64) * 1024 + kofs + k0 + lk8];
    u16x8 ki3 = *(const u16x8*)&K_i[(krow + 96) * 1024 + kofs + k0 + lk8];
    __syncthreads();
    *(u16x8*)&sQr[lrow][lk8] = q0;
    *(u16x8*)&sQr[lrow + 32][lk8] = q1;
    *(u16x8*)&sQi[lrow][lk8] = q2;
    *(u16x8*)&sQi[lrow + 32][lk8] = q3;
    *(u16x8*)&sKr[lrow][lk8] = kr0;
    *(u16x8*)&sKr[lrow + 32][lk8] = kr1;
    *(u16x8*)&sKr[lrow + 64][lk8] = kr2;
    *(u16x8*)&sKr[lrow + 96][lk8] = kr3;
    *(u16x8*)&sKi[lrow][lk8] = ki0;
    *(u16x8*)&sKi[lrow + 32][lk8] = ki1;
    *(u16x8*)&sKi[lrow + 64][lk8] = ki2;
    *(u16x8*)&sKi[lrow + 96][lk8] = ki3;
    __syncthreads();
#pragma unroll
    for (int kk = 0; kk < 64; kk += 16) {
      bf16x8 fQr = *(const bf16x8*)&sQr[srow_w + l31][kk + khalf];
      bf16x8 fQi = *(const bf16x8*)&sQi[srow_w + l31][kk + khalf];
      bf16x8 fKr0 = *(const bf16x8*)&sKr[tcol_w + l31][kk + khalf];
      bf16x8 fKr1 = *(const bf16x8*)&sKr[tcol_w + 32 + l31][kk + khalf];
      bf16x8 fKi0 = *(const bf16x8*)&sKi[tcol_w + l31][kk + khalf];
      bf16x8 fKi1 = *(const bf16x8*)&sKi[tcol_w + 32 + l31][kk + khalf];
      acc0 = __builtin_amdgcn_mfma_f32_32x32x16_bf16(fQr, fKr0, acc0, 0, 0, 0);
      acc0 = __builtin_amdgcn_mfma_f32_32x32x16_bf16(fQi, fKi0, acc0, 0, 0, 0);
      acc1 = __builtin_amdgcn_mfma_f32_32x32x16_bf16(fQr, fKr1, acc1, 0, 0, 0);
      acc1 = __builtin_amdgcn_mfma_f32_32x32x16_bf16(fQi, fKi1, acc1, 0, 0, 0);
    }
  }

  // ---- fused softmax over full 128-col rows ----
  __syncthreads();  // staging tiles dead; overlay stile
#pragma unroll
  for (int reg = 0; reg < 16; reg++) {
    int r = srow_w + (reg & 3) + 8 * (reg >> 2) + 4 * (lane >> 5);
    stile[r][tcol_w + l31] = acc0[reg] * SCALEF;
    stile[r][tcol_w + 32 + l31] = acc1[reg] * SCALEF;
  }
  __syncthreads();
  int row = tid >> 2;          // 0..63
  int quarter = tid & 3;       // cols quarter*32..+31
  float mx = -3.4e38f;
#pragma unroll
  for (int j = 0; j < 32; j++) mx = fmaxf(mx, stile[row][quarter * 32 + j]);
  mx = fmaxf(mx, __shfl_xor(mx, 1));
  mx = fmaxf(mx, __shfl_xor(mx, 2));
  float ev[32];
  float sum = 0.f;
#pragma unroll
  for (int j = 0; j < 32; j++) {
    ev[j] = expf(stile[row][quarter * 32 + j] - mx);
    sum += ev[j];
  }
  sum += __shfl_xor(sum, 1);
  sum += __shfl_xor(sum, 2);
  float inv = 1.f / sum;
  size_t prow = (size_t)(bm * SS + s_blk + row) * 256;
#pragma unroll
  for (int j = 0; j < 32; j++) {
    int c = quarter * 32 + j;
    u16 h, l;
    split_bf16(ev[j] * inv, h, l);
    Pb[prow + c] = h;
    Pb[prow + 128 + c] = l;
  }
}

// ---------------- P x V MFMA + gate -> pr/pi fp32 ----------------
__global__ __launch_bounds__(256) void k_pv(
    const u16* __restrict__ Pb, const u16* __restrict__ vbr, const u16* __restrict__ vbi,
    const float* __restrict__ gate_mask,
    float* __restrict__ pr, float* __restrict__ pi) {
  __shared__ u16 sP[64][LSTR], sVr[64][LSTR], sVi[64][LSTR];
  int bm = blockIdx.z;
  int m = bm & (MM - 1);
  int s_blk = blockIdx.y * 64;
  int o_blk = blockIdx.x * 64;
  int tid = threadIdx.x;
  int lrow = tid >> 3, lk8 = (tid & 7) << 3;
  size_t prow0 = (size_t)(bm * SS + s_blk + lrow), prow1 = prow0 + 32;

  int wave = tid >> 6, lane = tid & 63;
  int wrow = (wave >> 1) * 32;   // s
  int wcol = (wave & 1) * 32;    // d
  int l31 = lane & 31, khalf = (lane >> 5) * 8;

  f32x16 accR, accI;
  for (int i = 0; i < 16; i++) { accR[i] = 0.f; accI[i] = 0.f; }

  for (int it = 0; it < 6; ++it) {
    int seg = it >> 1, k0 = (it & 1) * 64;        // t-chunk
    int pofs = (seg == 1) ? 128 : 0;              // P lo half for seg1
    int vofs = (seg == 2) ? 512 : 0;              // V lo half for seg2
    u16x8 p0 = *(const u16x8*)&Pb[prow0 * 256 + pofs + k0 + lk8];
    u16x8 p1 = *(const u16x8*)&Pb[prow1 * 256 + pofs + k0 + lk8];
    size_t vrow0 = (size_t)(bm * SS + k0 + lrow), vrow1 = vrow0 + 32;
    u16x8 v0 = *(const u16x8*)&vbr[vrow0 * 1024 + vofs + o_blk + lk8];
    u16x8 v1 = *(const u16x8*)&vbr[vrow1 * 1024 + vofs + o_blk + lk8];
    u16x8 w0 = *(const u16x8*)&vbi[vrow0 * 1024 + vofs + o_blk + lk8];
    u16x8 w1 = *(const u16x8*)&vbi[vrow1 * 1024 + vofs + o_blk + lk8];
    __syncthreads();
    *(u16x8*)&sP[lrow][lk8] = p0;
    *(u16x8*)&sP[lrow + 32][lk8] = p1;
    *(u16x8*)&sVr[lrow][lk8] = v0;
    *(u16x8*)&sVr[lrow + 32][lk8] = v1;
    *(u16x8*)&sVi[lrow][lk8] = w0;
    *(u16x8*)&sVi[lrow + 32][lk8] = w1;
    __syncthreads();
#pragma unroll
    for (int kk = 0; kk < 64; kk += 16) {
      bf16x8 fP = *(const bf16x8*)&sP[wrow + l31][kk + khalf];
      u16x8 ar, ai;
#pragma unroll
      for (int j = 0; j < 8; j++) {
        ar[j] = sVr[kk + khalf + j][wcol + l31];  // transpose-on-read
        ai[j] = sVi[kk + khalf + j][wcol + l31];
      }
      accR = __builtin_amdgcn_mfma_f32_32x32x16_bf16(fP, __builtin_bit_cast(bf16x8, ar), accR, 0, 0, 0);
      accI = __builtin_amdgcn_mfma_f32_32x32x16_bf16(fP, __builtin_bit_cast(bf16x8, ai), accI, 0, 0, 0);
    }
  }

  int d = o_blk + wcol + l31;
  float g = 1.f / (1.f + expf(-gate_mask[m * DD + d]));
#pragma unroll
  for (int reg = 0; reg < 16; reg++) {
    int r_in = (reg & 3) + 8 * (reg >> 2) + 4 * (lane >> 5);
    size_t crow = (size_t)(bm * SS + s_blk + wrow + r_in);
    pr[crow * DD + d] = accR[reg] * g;
    pi[crow * DD + d] = accI[reg] * g;
  }
}

// ---------------- score/conf/halt heads ----------------
__global__ void k_heads(const float* __restrict__ pr, const float* __restrict__ pi,
                        const float* __restrict__ score_w, const float* __restrict__ score_b,
                        const float* __restrict__ conf_w, const float* __restrict__ conf_b,
                        const float* __restrict__ halt_w, const float* __restrict__ halt_b,
                        float* __restrict__ score, float* __restrict__ conf,
                        float* __restrict__ halt) {
  int row = blockIdx.x;            // (b*M+m)*S + s
  int m = (row >> 7) & (MM - 1);
  int tid = threadIdx.x;           // 256
  __shared__ float r0[256], r1[256], r2[256];
  float sp = 0.f, cp = 0.f, hp = 0.f;
#pragma unroll
  for (int i = 0; i < 4; i++) {
    int e = tid + i * 256;  // 0..1023
    float v = (e < DD) ? pr[(size_t)row * DD + e] : pi[(size_t)row * DD + e - DD];
    sp += v * score_w[m * 2 * DD + e];
    cp += v * conf_w[m * 2 * DD + e];
    hp += v * halt_w[m * 2 * DD + e];
  }
  r0[tid] = sp; r1[tid] = cp; r2[tid] = hp;
  __syncthreads();
  for (int off = 128; off > 0; off >>= 1) {
    if (tid < off) { r0[tid] += r0[tid + off]; r1[tid] += r1[tid + off]; r2[tid] += r2[tid + off]; }
    __syncthreads();
  }
  if (tid == 0) {
    score[row] = r0[0] + score_b[m];
    conf[row] = 1.f / (1.f + expf(-(r1[0] + conf_b[m])));
    halt[row] = r2[0] + halt_b[m];
  }
}

// ---------------- magnitude LN + phase renorm + mod scale -> split bf16 ----------------
__global__ void k_lnphase(const float* __restrict__ zr, const float* __restrict__ zi,
                          const float* __restrict__ ln_scale, const float* __restrict__ ln_shift,
                          const float* __restrict__ mod_bias,
                          u16* __restrict__ zbr, u16* __restrict__ zbi) {
  int row = blockIdx.x;            // (b*M+m)*S + s
  int m = (row >> 7) & (MM - 1);
  int tid = threadIdx.x;           // 128
  size_t base = (size_t)row * DD;
  float zrv[4], ziv[4], rv[4];
  float sum = 0.f, sumsq = 0.f;
#pragma unroll
  for (int i = 0; i < 4; i++) {
    int o = tid + i * 128;
    float a = zr[base + o], bv = zi[base + o];
    zrv[i] = a; ziv[i] = bv;
    float r = sqrtf(a * a + bv * bv);
    rv[i] = r;
    float mg = r + EPSF;
    sum += mg;
    sumsq += mg * mg;
  }
  __shared__ float rs[128], rq[128];
  rs[tid] = sum; rq[tid] = sumsq;
  __syncthreads();
  for (int off = 64; off > 0; off >>= 1) {
    if (tid < off) { rs[tid] += rs[tid + off]; rq[tid] += rq[tid + off]; }
    __syncthreads();
  }
  float mean = rs[0] * (1.0f / DD);
  float var = (rq[0] - (float)DD * mean * mean) * (1.0f / (DD - 1));
  float inv = 1.0f / sqrtf(var + EPSF);
#pragma unroll
  for (int i = 0; i < 4; i++) {
    int o = tid + i * 128;
    float mg = rv[i] + EPSF;
    float nm = (mg - mean) * inv * ln_scale[m * DD + o] + ln_shift[m * DD + o];
    float r = rv[i];
    float cosp, sinp;
    if (r > 0.f) { cosp = zrv[i] / r; sinp = ziv[i] / r; }
    else { cosp = 1.f; sinp = 0.f; }
    float z1r = nm * cosp, z1i = nm * sinp;
    float nrm = sqrtf(z1r * z1r + z1i * z1i) + EPSF;
    float sc = fmaxf(nrm + mod_bias[m * DD + o], 0.f) / nrm;
    u16 h, l;
    split_bf16(z1r * sc, h, l);
    zbr[(size_t)row * 1024 + o] = h;
    zbr[(size_t)row * 1024 + 512 + o] = l;
    split_bf16(z1i * sc, h, l);
    zbi[(size_t)row * 1024 + o] = h;
    zbi[(size_t)row * 1024 + 512 + o] = l;
  }
}

// ---------------- stack mem update + read + st dot partials ----------------
__global__ void k_memup(const float* __restrict__ flat_in,
                        const float* __restrict__ nptrg, const float* __restrict__ wmg,
                        float* __restrict__ memv, float* __restrict__ readv,
                        const float* __restrict__ st_score_w, const float* __restrict__ st_conf_w,
                        float* __restrict__ stacc) {
  int b = blockIdx.x >> 2;
  int chunk = blockIdx.x & 3;
  int tid = threadIdx.x;           // 256
  int e = chunk * 256 + tid;       // 0..1023
  __shared__ float nptr[KK], wm[KK];
  __shared__ float red[256], red2[256];
  if (tid < KK) { nptr[tid] = nptrg[b * KK + tid]; wm[tid] = wmg[b * KK + tid]; }
  __syncthreads();
  float fl = flat_in[b * 2 * DD + e];
  float racc = 0.f;
#pragma unroll
  for (int k = 0; k < KK; k++) {
    size_t idx = ((size_t)(b * KK + k)) * 2 * DD + e;
    float nm = wm[k] * fl + memv[idx] * (1.f - wm[k]);
    memv[idx] = nm;
    racc += nm * nptr[k];
  }
  readv[b * 2 * DD + e] = racc;
  red[tid] = racc * st_score_w[e];
  red2[tid] = racc * st_conf_w[e];
  __syncthreads();
  for (int off = 128; off > 0; off >>= 1) {
    if (tid < off) { red[tid] += red[tid + off]; red2[tid] += red2[tid + off]; }
    __syncthreads();
  }
  if (tid == 0) {
    atomicAdd(&stacc[b * 2], red[0]);
    atomicAdd(&stacc[b * 2 + 1], red2[0]);
  }
}

// ---------------- halt p + stv finalize ----------------
__global__ void k_haltp(const float* __restrict__ halt, float* __restrict__ rem,
                        float* __restrict__ coeff, const float* __restrict__ stacc,
                        const float* __restrict__ st_score_b, const float* __restrict__ st_conf_b,
                        float* __restrict__ stv) {
  int b = blockIdx.x;
  int tid = threadIdx.x;  // 256
  __shared__ float red[256];
  float v0 = halt[b * MM * SS + tid];
  float v1 = halt[b * MM * SS + 256 + tid];
  red[tid] = 1.f / (1.f + expf(-v0)) + 1.f / (1.f + expf(-v1));
  __syncthreads();
  for (int off = 128; off > 0; off >>= 1) {
    if (tid < off) red[tid] += red[tid + off];
    __syncthreads();
  }
  if (tid == 0) {
    float p = red[0] * (1.0f / (MM * SS));
    float r = rem[b];
    coeff[b] = p * r;
    rem[b] = r * (1.f - p);
    stv[b] = stacc[b * 2] + st_score_b[0];
    stv[BB + b] = 1.f / (1.f + expf(-(stacc[b * 2 + 1] + st_conf_b[0])));
  }
}

// ---------------- module-mix softmax + new state + acc + next-step c ----------------
__global__ void k_combine(const float* __restrict__ pr, const float* __restrict__ pi,
                          const float* __restrict__ score, const float* __restrict__ conf,
                          const float* __restrict__ stv, const float* __restrict__ readv,
                          const float* __restrict__ coeff,
                          const float* __restrict__ xr, const float* __restrict__ xi,
                          float* __restrict__ sr, float* __restrict__ si, float* __restrict__ acc,
                          u16* __restrict__ crbf, u16* __restrict__ cibf) {
  int bs = blockIdx.x;             // b*S + s
  int b = bs >> 7, s = bs & (SS - 1);
  int tid = threadIdx.x;           // 256
  __shared__ float w[5];
  if (tid == 0) {
    float l[5];
    for (int m = 0; m < MM; m++) {
      int r = (b * MM + m) * SS + s;
      l[m] = score[r] * conf[r];
    }
    l[4] = stv[b] * stv[BB + b];
    float mx = l[0];
    for (int j = 1; j < 5; j++) mx = fmaxf(mx, l[j]);
    float sum = 0.f;
    for (int j = 0; j < 5; j++) { l[j] = expf(l[j] - mx); sum += l[j]; }
    for (int j = 0; j < 5; j++) w[j] = l[j] / sum;
  }
  __syncthreads();
  float cf = coeff[b];
#pragma unroll
  for (int i = 0; i < 2; i++) {
    int d = tid + i * 256;
    float nsr = w[4] * readv[b * 2 * DD + d];
    float nsi = w[4] * readv[b * 2 * DD + DD + d];
#pragma unroll
    for (int m = 0; m < MM; m++) {
      size_t off = ((size_t)((b * MM + m) * SS + s)) * DD + d;
      nsr += w[m] * pr[off];
      nsi += w[m] * pi[off];
    }
    size_t sidx = (size_t)bs * DD + d;
    sr[sidx] = nsr;
    si[sidx] = nsi;
    size_t aoff = (size_t)bs * 2 * DD;
    acc[aoff + d] += cf * nsr;
    acc[aoff + DD + d] += cf * nsi;
    u16 h, l;
    split_bf16(0.5f * xr[sidx] + 0.5f * nsr, h, l);
    crbf[(size_t)bs * 1024 + d] = h;
    crbf[(size_t)bs * 1024 + 512 + d] = l;
    split_bf16(0.5f * xi[sidx] + 0.5f * nsi, h, l);
    cibf[(size_t)bs * 1024 + d] = h;
    cibf[(size_t)bs * 1024 + 512 + d] = l;
  }
}

// ---------------- out = acc + rem * concat(sr, si) ----------------
__global__ void k_final(const float* __restrict__ acc, const float* __restrict__ rem,
                        const float* __restrict__ sr, const float* __restrict__ si,
                        float* __restrict__ out) {
  int idx = blockIdx.x * 256 + threadIdx.x;  // < B*S*2D
  int e = idx & (2 * DD - 1);
  int bs = idx >> 10;
  int b = bs >> 7;
  float v = (e < DD) ? sr[(size_t)bs * DD + e] : si[(size_t)bs * DD + e - DD];
  out[idx] = acc[idx] + rem[b] * v;
}

extern "C" void kernel_launch(void* const* d_in, const int* in_sizes, int n_in,
                              void* d_out, int out_size, void* d_ws, size_t ws_size,
                              hipStream_t stream) {
  const float* xr = (const float*)d_in[0];
  const float* xi = (const float*)d_in[1];
  const float* Wl_r = (const float*)d_in[2];
  const float* Wl_i = (const float*)d_in[3];
  const float* Wq_r = (const float*)d_in[4];
  const float* Wq_i = (const float*)d_in[5];
  const float* Wk_r = (const float*)d_in[6];
  const float* Wk_i = (const float*)d_in[7];
  const float* Wv_r = (const float*)d_in[8];
  const float* Wv_i = (const float*)d_in[9];
  const float* ln_scale = (const float*)d_in[10];
  const float* ln_shift = (const float*)d_in[11];
  const float* mod_bias = (const float*)d_in[12];
  const float* gate_mask = (const float*)d_in[13];
  const float* score_w = (const float*)d_in[14];
  const float* score_b = (const float*)d_in[15];
  const float* conf_w = (const float*)d_in[16];
  const float* conf_b = (const float*)d_in[17];
  const float* halt_w = (const float*)d_in[18];
  const float* halt_b = (const float*)d_in[19];
  const float* ctrl_w = (const float*)d_in[20];
  const float* ctrl_b = (const float*)d_in[21];
  const float* st_score_w = (const float*)d_in[22];
  const float* st_score_b = (const float*)d_in[23];
  const float* st_conf_w = (const float*)d_in[24];
  const float* st_conf_b = (const float*)d_in[25];
  float* out = (float*)d_out;

  const int BSD = BB * SS * DD;        // 262144
  const int BMSD = BB * MM * SS * DD;  // 1048576
  const size_t WSLOT = (size_t)MM * DD * 1024;  // u16 per weight matrix

  char* pc = (char*)d_ws;
  float* sr = (float*)pc; pc += (size_t)BSD * 4;
  float* si = (float*)pc; pc += (size_t)BSD * 4;
  float* zr = (float*)pc; pc += (size_t)BMSD * 4;
  float* zi = (float*)pc; pc += (size_t)BMSD * 4;
  float* prb = (float*)pc; pc += (size_t)BMSD * 4;
  float* pib = (float*)pc; pc += (size_t)BMSD * 4;
  float* scorev = (float*)pc; pc += (size_t)BB * MM * SS * 4;
  float* confv = (float*)pc; pc += (size_t)BB * MM * SS * 4;
  float* haltv = (float*)pc; pc += (size_t)BB * MM * SS * 4;
  float* flat = (float*)pc; pc += (size_t)BB * 2 * DD * 4;
  float* stacc = (float*)pc; pc += 64;
  float* nptrg = (float*)pc; pc += (size_t)BB * KK * 4;
  float* wmg = (float*)pc; pc += (size_t)BB * KK * 4;
  float* memv = (float*)pc; pc += (size_t)BB * KK * 2 * DD * 4;
  float* ptrv = (float*)pc; pc += (size_t)BB * KK * 4;
  float* readv = (float*)pc; pc += (size_t)BB * 2 * DD * 4;
  float* stv = (float*)pc; pc += (size_t)2 * BB * 4;
  float* accb = (float*)pc; pc += (size_t)BB * SS * 2 * DD * 4;
  float* rem = (float*)pc; pc += (size_t)BB * 4;
  float* coeff = (float*)pc; pc += (size_t)BB * 4;
  u16* crbf = (u16*)pc; pc += (size_t)BB * SS * 1024 * 2;
  u16* cibf = (u16*)pc; pc += (size_t)BB * SS * 1024 * 2;
  u16* zbr = (u16*)pc; pc += (size_t)BB * MM * SS * 1024 * 2;
  u16* zbi = (u16*)pc; pc += (size_t)BB * MM * SS * 1024 * 2;
  u16* qbr = (u16*)pc; pc += (size_t)BB * MM * SS * 1024 * 2;
  u16* qbi = (u16*)pc; pc += (size_t)BB * MM * SS * 1024 * 2;
  u16* kbr = (u16*)pc; pc += (size_t)BB * MM * SS * 1024 * 2;
  u16* kbi = (u16*)pc; pc += (size_t)BB * MM * SS * 1024 * 2;
  u16* vbr = (u16*)pc; pc += (size_t)BB * MM * SS * 1024 * 2;
  u16* vbi = (u16*)pc; pc += (size_t)BB * MM * SS * 1024 * 2;
  u16* Pb  = (u16*)pc; pc += (size_t)BB * MM * SS * 256 * 2;
  u16* wbf = (u16*)pc; pc += 8 * WSLOT * 2;

  // one-time (per launch) weight conversion
  k_convw<<<4096, 256, 0, stream>>>(Wl_r, wbf + 0 * WSLOT);
  k_convw<<<4096, 256, 0, stream>>>(Wl_i, wbf + 1 * WSLOT);
  k_convw<<<4096, 256, 0, stream>>>(Wq_r, wbf + 2 * WSLOT);
  k_convw<<<4096, 256, 0, stream>>>(Wq_i, wbf + 3 * WSLOT);
  k_convw<<<4096, 256, 0, stream>>>(Wk_r, wbf + 4 * WSLOT);
  k_convw<<<4096, 256, 0, stream>>>(Wk_i, wbf + 5 * WSLOT);
  k_convw<<<4096, 256, 0, stream>>>(Wv_r, wbf + 6 * WSLOT);
  k_convw<<<4096, 256, 0, stream>>>(Wv_i, wbf + 7 * WSLOT);

  k_init<<<2048, 256, 0, stream>>>(xr, xi, sr, si, accb, memv, ptrv, rem, crbf, cibf);

  dim3 ggrid(DD / 64, (BB * SS) / 64, MM);        // 256 blocks
  dim3 qgrid(DD / 64, (BB * SS) / 64, MM * 3);    // 768 blocks
  dim3 smgrid(1, SS / 64, BB * MM);               // 32 blocks
  dim3 pvgrid(DD / 64, SS / 64, BB * MM);         // 256 blocks

  for (int step = 0; step < NSTEPS; ++step) {
    k_flatctrl<<<BB, 256, 0, stream>>>(sr, si, ctrl_w, ctrl_b, ptrv, flat, nptrg, wmg, stacc);
    k_gemm_mfma<<<ggrid, 256, 0, stream>>>(crbf, cibf, wbf + 0 * WSLOT, wbf + 1 * WSLOT, zr, zi);
    k_lnphase<<<BB * MM * SS, 128, 0, stream>>>(zr, zi, ln_scale, ln_shift, mod_bias, zbr, zbi);
    k_gemm_qkv<<<qgrid, 256, 0, stream>>>(zbr, zbi, wbf, WSLOT, qbr, qbi, kbr, kbi, vbr, vbi);
    k_scores_sm<<<smgrid, 256, 0, stream>>>(qbr, qbi, kbr, kbi, Pb);
    k_pv<<<pvgrid, 256, 0, stream>>>(Pb, vbr, vbi, gate_mask, prb, pib);
    k_heads<<<BB * MM * SS, 256, 0, stream>>>(prb, pib, score_w, score_b, conf_w, conf_b,
                                              halt_w, halt_b, scorev, confv, haltv);
    k_memup<<<BB * 4, 256, 0, stream>>>(flat, nptrg, wmg, memv, readv,
                                        st_score_w, st_conf_w, stacc);
    k_haltp<<<BB, 256, 0, stream>>>(haltv, rem, coeff, stacc, st_score_b, st_conf_b, stv);
    k_combine<<<BB * SS, 256, 0, stream>>>(prb, pib, scorev, confv, stv, readv, coeff,
                                           xr, xi, sr, si, accb, crbf, cibf);
  }

  k_final<<<(BB * SS * 2 * DD) / 256, 256, 0, stream>>>(accb, rem, sr, si, out);
}